// Round 1
// baseline (304.382 us; speedup 1.0000x reference)
//
#include <hip/hip_runtime.h>
#include <math.h>

#define N_NODES 1024
#define T_STEPS 36
#define QT 64          // q rows per block (kernel 2)
#define KT 64          // k rows per LDS tile
#define KSTR 20        // Ks/Vs row stride in floats (16 data + 4 pad; 80B keeps b128 align, banks conflict-free with strided k)
#define PSTR 70        // Ps row stride in floats (64 data + 6 pad; 280B keeps b64 align, ~2-way worst)

// ---------------------------------------------------------------------------
// Kernel 1: per-head input projections  out[t][n][h*16+e] = sum_d in[n][t][h*16+d] * W[e][d]
// (nn.Linear with no bias: x @ W.T), with [n][t] -> [t][n] transpose so the
// attention kernel reads contiguous N-slabs per t.
// ---------------------------------------------------------------------------
__global__ __launch_bounds__(256) void proj_kernel(
    const float* __restrict__ vin, const float* __restrict__ kin, const float* __restrict__ qin,
    const float* __restrict__ Wv, const float* __restrict__ Wk, const float* __restrict__ Wq,
    float* __restrict__ vp, float* __restrict__ kp, float* __restrict__ qp)
{
    __shared__ float sW[256];
    const float* in; const float* W; float* out;
    if (blockIdx.y == 0)      { in = vin; W = Wv; out = vp; }
    else if (blockIdx.y == 1) { in = kin; W = Wk; out = kp; }
    else                      { in = qin; W = Wq; out = qp; }
    const int tid = threadIdx.x;
    sW[tid] = W[tid];
    __syncthreads();

    const int p = blockIdx.x * 256 + tid;        // p = n*T + t (input row index)
    const int n = p / T_STEPS;
    const int t = p - n * T_STEPS;

    float r[64];
    const float4* src = (const float4*)(in + (size_t)p * 64);
    #pragma unroll
    for (int i = 0; i < 16; ++i) {
        float4 v = src[i];
        r[4*i+0] = v.x; r[4*i+1] = v.y; r[4*i+2] = v.z; r[4*i+3] = v.w;
    }

    float4* dst = (float4*)(out + ((size_t)t * N_NODES + n) * 64);
    #pragma unroll
    for (int h = 0; h < 4; ++h) {
        float o[16];
        #pragma unroll
        for (int e = 0; e < 16; ++e) {
            float acc = 0.f;
            #pragma unroll
            for (int d = 0; d < 16; d += 4) {
                float4 w = *(const float4*)&sW[e*16 + d];
                acc = fmaf(r[h*16+d+0], w.x, acc);
                acc = fmaf(r[h*16+d+1], w.y, acc);
                acc = fmaf(r[h*16+d+2], w.z, acc);
                acc = fmaf(r[h*16+d+3], w.w, acc);
            }
            o[e] = acc;
        }
        #pragma unroll
        for (int i = 0; i < 4; ++i)
            dst[h*4 + i] = make_float4(o[4*i+0], o[4*i+1], o[4*i+2], o[4*i+3]);
    }
}

// ---------------------------------------------------------------------------
// Kernel 2: flash attention over the node axis, per (t, h, q-tile of 64).
// Q rows held in registers; K/V tiles staged in LDS; P round-trips via LDS.
// Thread org (256 thr): S-phase tid = rg*8+cg (32 rowgroups x 8 colgroups,
// thread tile 2 q-rows x 8 k, k = cg+8j strided -> conflict-free K reads).
// PV-phase tid = rg*8 + dg*4 + kc (2 d-groups of 8 feats x 4 k-chunks,
// k = 4i+kc strided), partials reduced over kc by shfl_xor at the end.
// ---------------------------------------------------------------------------
__global__ __launch_bounds__(256) void attn_kernel(
    const float* __restrict__ qp, const float* __restrict__ kp, const float* __restrict__ vp,
    float* __restrict__ ob)
{
    __shared__ float Ks[KT * KSTR];
    __shared__ float Vs[KT * KSTR];
    __shared__ float Ps[KT * PSTR];

    const int tid = threadIdx.x;
    const int q0 = blockIdx.x * QT;
    const int h  = blockIdx.y;
    const int t  = blockIdx.z;
    const int rg = tid >> 3;          // 0..31
    const int cg = tid & 7;           // 0..7
    const int dg = (tid >> 2) & 1;    // 0..1
    const int kc = tid & 3;           // 0..3

    // Q rows (2 per thread) -> registers, once per block
    float qreg[2][16];
    {
        const float* qb = qp + ((size_t)t * N_NODES + q0 + 2*rg) * 64 + h * 16;
        #pragma unroll
        for (int rr = 0; rr < 2; ++rr)
            #pragma unroll
            for (int c = 0; c < 4; ++c) {
                float4 v = *(const float4*)(qb + rr*64 + c*4);
                qreg[rr][4*c+0] = v.x; qreg[rr][4*c+1] = v.y;
                qreg[rr][4*c+2] = v.z; qreg[rr][4*c+3] = v.w;
            }
    }

    float m0 = -INFINITY, m1 = -INFINITY, l0 = 0.f, l1 = 0.f;
    float o[2][8];
    #pragma unroll
    for (int dd = 0; dd < 8; ++dd) { o[0][dd] = 0.f; o[1][dd] = 0.f; }

    const float scale = 0.18033688011112042f;   // log2(e) / sqrt(EMBED=64)
    const int srow = tid >> 2, sq = tid & 3;    // staging: 64 rows x 4 float4
    const float* kb = kp + (size_t)t * N_NODES * 64 + h * 16;
    const float* vb = vp + (size_t)t * N_NODES * 64 + h * 16;

    for (int kt = 0; kt < N_NODES; kt += KT) {
        __syncthreads();   // protect Ks/Vs/Ps against previous iteration's readers
        *(float4*)&Ks[srow*KSTR + sq*4] = *(const float4*)(kb + (size_t)(kt + srow)*64 + sq*4);
        *(float4*)&Vs[srow*KSTR + sq*4] = *(const float4*)(vb + (size_t)(kt + srow)*64 + sq*4);
        __syncthreads();

        // ---- S = Q.K^T (scaled into exp2 domain) ----
        float s[2][8];
        #pragma unroll
        for (int j = 0; j < 8; ++j) {
            const int k = cg + 8*j;
            const float* kr = &Ks[k*KSTR];
            const float4 a = *(const float4*)(kr + 0);
            const float4 b = *(const float4*)(kr + 4);
            const float4 c = *(const float4*)(kr + 8);
            const float4 d = *(const float4*)(kr + 12);
            #pragma unroll
            for (int rr = 0; rr < 2; ++rr) {
                float acc = qreg[rr][0]*a.x;
                acc = fmaf(qreg[rr][1],  a.y, acc);
                acc = fmaf(qreg[rr][2],  a.z, acc);
                acc = fmaf(qreg[rr][3],  a.w, acc);
                acc = fmaf(qreg[rr][4],  b.x, acc);
                acc = fmaf(qreg[rr][5],  b.y, acc);
                acc = fmaf(qreg[rr][6],  b.z, acc);
                acc = fmaf(qreg[rr][7],  b.w, acc);
                acc = fmaf(qreg[rr][8],  c.x, acc);
                acc = fmaf(qreg[rr][9],  c.y, acc);
                acc = fmaf(qreg[rr][10], c.z, acc);
                acc = fmaf(qreg[rr][11], c.w, acc);
                acc = fmaf(qreg[rr][12], d.x, acc);
                acc = fmaf(qreg[rr][13], d.y, acc);
                acc = fmaf(qreg[rr][14], d.z, acc);
                acc = fmaf(qreg[rr][15], d.w, acc);
                s[rr][j] = acc * scale;
            }
        }

        // ---- online softmax (exp2 domain) ----
        float tm0 = s[0][0], tm1 = s[1][0];
        #pragma unroll
        for (int j = 1; j < 8; ++j) { tm0 = fmaxf(tm0, s[0][j]); tm1 = fmaxf(tm1, s[1][j]); }
        #pragma unroll
        for (int mask = 1; mask < 8; mask <<= 1) {
            tm0 = fmaxf(tm0, __shfl_xor(tm0, mask));
            tm1 = fmaxf(tm1, __shfl_xor(tm1, mask));
        }
        const float mn0 = fmaxf(m0, tm0), mn1 = fmaxf(m1, tm1);
        const float a0 = exp2f(m0 - mn0), a1 = exp2f(m1 - mn1);
        float pbuf[2][8];
        float ts0 = 0.f, ts1 = 0.f;
        #pragma unroll
        for (int j = 0; j < 8; ++j) {
            const float p0 = exp2f(s[0][j] - mn0);
            const float p1 = exp2f(s[1][j] - mn1);
            pbuf[0][j] = p0; pbuf[1][j] = p1;
            ts0 += p0; ts1 += p1;
        }
        #pragma unroll
        for (int mask = 1; mask < 8; mask <<= 1) {
            ts0 += __shfl_xor(ts0, mask);
            ts1 += __shfl_xor(ts1, mask);
        }
        l0 = l0*a0 + ts0; l1 = l1*a1 + ts1;
        m0 = mn0; m1 = mn1;

        #pragma unroll
        for (int j = 0; j < 8; ++j) {
            const int k = cg + 8*j;
            *(float2*)&Ps[k*PSTR + 2*rg] = make_float2(pbuf[0][j], pbuf[1][j]);
        }
        #pragma unroll
        for (int dd = 0; dd < 8; ++dd) { o[0][dd] *= a0; o[1][dd] *= a1; }
        __syncthreads();

        // ---- O += P.V (k-chunked) ----
        #pragma unroll
        for (int i = 0; i < 16; ++i) {
            const int k = 4*i + kc;
            const float2 pv = *(const float2*)&Ps[k*PSTR + 2*rg];
            const float4 v0 = *(const float4*)&Vs[k*KSTR + dg*8 + 0];
            const float4 v1 = *(const float4*)&Vs[k*KSTR + dg*8 + 4];
            o[0][0] = fmaf(pv.x, v0.x, o[0][0]);
            o[0][1] = fmaf(pv.x, v0.y, o[0][1]);
            o[0][2] = fmaf(pv.x, v0.z, o[0][2]);
            o[0][3] = fmaf(pv.x, v0.w, o[0][3]);
            o[0][4] = fmaf(pv.x, v1.x, o[0][4]);
            o[0][5] = fmaf(pv.x, v1.y, o[0][5]);
            o[0][6] = fmaf(pv.x, v1.z, o[0][6]);
            o[0][7] = fmaf(pv.x, v1.w, o[0][7]);
            o[1][0] = fmaf(pv.y, v0.x, o[1][0]);
            o[1][1] = fmaf(pv.y, v0.y, o[1][1]);
            o[1][2] = fmaf(pv.y, v0.z, o[1][2]);
            o[1][3] = fmaf(pv.y, v0.w, o[1][3]);
            o[1][4] = fmaf(pv.y, v1.x, o[1][4]);
            o[1][5] = fmaf(pv.y, v1.y, o[1][5]);
            o[1][6] = fmaf(pv.y, v1.z, o[1][6]);
            o[1][7] = fmaf(pv.y, v1.w, o[1][7]);
        }
    }

    // reduce the 4 k-chunk partials (shfl over kc = tid bits 0..1)
    #pragma unroll
    for (int dd = 0; dd < 8; ++dd) {
        #pragma unroll
        for (int mask = 1; mask < 4; mask <<= 1) {
            o[0][dd] += __shfl_xor(o[0][dd], mask);
            o[1][dd] += __shfl_xor(o[1][dd], mask);
        }
    }
    if (kc == 0) {
        const float inv0 = 1.f / l0, inv1 = 1.f / l1;
        float* r0 = ob + ((size_t)(q0 + 2*rg + 0) * T_STEPS + t) * 64 + h*16 + dg*8;
        float* r1 = ob + ((size_t)(q0 + 2*rg + 1) * T_STEPS + t) * 64 + h*16 + dg*8;
        *(float4*)(r0 + 0) = make_float4(o[0][0]*inv0, o[0][1]*inv0, o[0][2]*inv0, o[0][3]*inv0);
        *(float4*)(r0 + 4) = make_float4(o[0][4]*inv0, o[0][5]*inv0, o[0][6]*inv0, o[0][7]*inv0);
        *(float4*)(r1 + 0) = make_float4(o[1][0]*inv1, o[1][1]*inv1, o[1][2]*inv1, o[1][3]*inv1);
        *(float4*)(r1 + 4) = make_float4(o[1][4]*inv1, o[1][5]*inv1, o[1][6]*inv1, o[1][7]*inv1);
    }
}

// ---------------------------------------------------------------------------
// Kernel 3: out[p][j] = sum_e ob[p][e] * Wo[j][e] + bo[j]
// ---------------------------------------------------------------------------
__global__ __launch_bounds__(256) void outproj_kernel(
    const float* __restrict__ ob, const float* __restrict__ Wo, const float* __restrict__ bo,
    float* __restrict__ out)
{
    __shared__ float sW[64*64];
    __shared__ float sb[64];
    const int tid = threadIdx.x;
    #pragma unroll
    for (int i = 0; i < 16; ++i) sW[tid + 256*i] = Wo[tid + 256*i];
    if (tid < 64) sb[tid] = bo[tid];
    __syncthreads();

    const int p = blockIdx.x * 256 + tid;
    float r[64];
    const float4* src = (const float4*)(ob + (size_t)p * 64);
    #pragma unroll
    for (int i = 0; i < 16; ++i) {
        float4 v = src[i];
        r[4*i+0] = v.x; r[4*i+1] = v.y; r[4*i+2] = v.z; r[4*i+3] = v.w;
    }
    float4* dst = (float4*)(out + (size_t)p * 64);
    #pragma unroll 2
    for (int j4 = 0; j4 < 16; ++j4) {
        float acc0 = sb[j4*4+0], acc1 = sb[j4*4+1], acc2 = sb[j4*4+2], acc3 = sb[j4*4+3];
        #pragma unroll
        for (int e = 0; e < 64; e += 4) {
            const float4 w0 = *(const float4*)&sW[(j4*4+0)*64 + e];
            const float4 w1 = *(const float4*)&sW[(j4*4+1)*64 + e];
            const float4 w2 = *(const float4*)&sW[(j4*4+2)*64 + e];
            const float4 w3 = *(const float4*)&sW[(j4*4+3)*64 + e];
            acc0 = fmaf(r[e+0], w0.x, acc0); acc0 = fmaf(r[e+1], w0.y, acc0);
            acc0 = fmaf(r[e+2], w0.z, acc0); acc0 = fmaf(r[e+3], w0.w, acc0);
            acc1 = fmaf(r[e+0], w1.x, acc1); acc1 = fmaf(r[e+1], w1.y, acc1);
            acc1 = fmaf(r[e+2], w1.z, acc1); acc1 = fmaf(r[e+3], w1.w, acc1);
            acc2 = fmaf(r[e+0], w2.x, acc2); acc2 = fmaf(r[e+1], w2.y, acc2);
            acc2 = fmaf(r[e+2], w2.z, acc2); acc2 = fmaf(r[e+3], w2.w, acc2);
            acc3 = fmaf(r[e+0], w3.x, acc3); acc3 = fmaf(r[e+1], w3.y, acc3);
            acc3 = fmaf(r[e+2], w3.z, acc3); acc3 = fmaf(r[e+3], w3.w, acc3);
        }
        dst[j4] = make_float4(acc0, acc1, acc2, acc3);
    }
}

// ---------------------------------------------------------------------------
extern "C" void kernel_launch(void* const* d_in, const int* in_sizes, int n_in,
                              void* d_out, int out_size, void* d_ws, size_t ws_size,
                              hipStream_t stream)
{
    (void)in_sizes; (void)n_in; (void)out_size; (void)ws_size;
    const float* values = (const float*)d_in[0];
    const float* keys   = (const float*)d_in[1];
    const float* query  = (const float*)d_in[2];
    const float* Wv     = (const float*)d_in[3];
    const float* Wk     = (const float*)d_in[4];
    const float* Wq     = (const float*)d_in[5];
    const float* Wo     = (const float*)d_in[6];
    const float* bo     = (const float*)d_in[7];

    float* ws = (float*)d_ws;
    const size_t TN64 = (size_t)N_NODES * T_STEPS * 64;   // 2,359,296 floats
    float* vp   = ws;
    float* kp   = ws + TN64;
    float* qp   = ws + 2*TN64;
    float* obuf = ws + 3*TN64;   // total ws use: 4*TN64*4B = 37.7 MB

    proj_kernel<<<dim3(144, 3, 1), 256, 0, stream>>>(values, keys, query, Wv, Wk, Wq, vp, kp, qp);
    attn_kernel<<<dim3(N_NODES/QT, 4, T_STEPS), 256, 0, stream>>>(qp, kp, vp, obuf);
    outproj_kernel<<<dim3(144, 1, 1), 256, 0, stream>>>(obuf, Wo, bo, (float*)d_out);
}

// Round 2
// 208.578 us; speedup vs baseline: 1.4593x; 1.4593x over previous
//
#include <hip/hip_runtime.h>
#include <math.h>

#define N_NODES 1024
#define T_STEPS 36
#define KTILE   128          // k-nodes per attn LDS tile
#define KSTR2   24           // K LDS row stride (bf16 units): 16 data + 8 pad, 48B (16B-aligned, bank-uniform)
#define VTSTR   136          // V^T / P LDS row stride (bf16): 128 data + 8 pad, 272B (16B-aligned, bank-uniform)
#define PSTR2   136

typedef __bf16  bf16x8 __attribute__((ext_vector_type(8)));
typedef float   f32x4  __attribute__((ext_vector_type(4)));

#define MFMA_16x16x32_BF16 __builtin_amdgcn_mfma_f32_16x16x32_bf16

// fp32 -> bf16 RNE (bit-level, no header dependence)
__device__ __forceinline__ unsigned short bf16_rne(float f) {
    unsigned int u = __float_as_uint(f);
    u += 0x7FFFu + ((u >> 16) & 1u);
    return (unsigned short)(u >> 16);
}
__device__ __forceinline__ float bf16_tof(unsigned short h) {
    return __uint_as_float(((unsigned int)h) << 16);
}

// ---------------------------------------------------------------------------
// Kernel 1: per-head projections -> split bf16 hi/lo planes.
//   qhi/qlo, khi/klo : [t][h][n][16]   (q pre-scaled by log2(e)/8)
//   vthi/vtlo        : [t][h][d][n]    (transposed for PV B-fragments)
// Block = (n-chunk of 64, t); thread (r=tid>>2 row, c=tid&3 head).
// ---------------------------------------------------------------------------
__global__ __launch_bounds__(256) void proj2_kernel(
    const float* __restrict__ vin, const float* __restrict__ kin, const float* __restrict__ qin,
    const float* __restrict__ Wv, const float* __restrict__ Wk, const float* __restrict__ Wq,
    unsigned short* __restrict__ qhi, unsigned short* __restrict__ qlo,
    unsigned short* __restrict__ khi, unsigned short* __restrict__ klo,
    unsigned short* __restrict__ vthi, unsigned short* __restrict__ vtlo)
{
    __shared__ float sWv[256], sWk[256], sWq[256];
    const int tid = threadIdx.x;
    sWv[tid] = Wv[tid]; sWk[tid] = Wk[tid]; sWq[tid] = Wq[tid];
    __syncthreads();

    const int r = tid >> 2, c = tid & 3;          // row-in-chunk, head
    const int t = blockIdx.y;
    const int n = blockIdx.x * 64 + r;
    const int th = t * 4 + c;
    const size_t ibase = ((size_t)n * T_STEPS + t) * 64 + c * 16;
    const float QSCALE = 0.18033688011112042f;    // log2(e)/sqrt(64)

    float x[16], y[16];
    union { unsigned short u[16]; uint4 v[2]; } hb, lb;

    // ---- Q ----
    #pragma unroll
    for (int i = 0; i < 4; ++i) { float4 f = *(const float4*)(qin + ibase + 4*i);
        x[4*i]=f.x; x[4*i+1]=f.y; x[4*i+2]=f.z; x[4*i+3]=f.w; }
    #pragma unroll
    for (int e = 0; e < 16; ++e) { float a = 0.f;
        #pragma unroll
        for (int d = 0; d < 16; ++d) a = fmaf(x[d], sWq[e*16+d], a);
        y[e] = a * QSCALE; }
    #pragma unroll
    for (int e = 0; e < 16; ++e) { unsigned short h = bf16_rne(y[e]);
        hb.u[e] = h; lb.u[e] = bf16_rne(y[e] - bf16_tof(h)); }
    { uint4* dh = (uint4*)(qhi + ((size_t)th*N_NODES + n)*16);
      uint4* dl = (uint4*)(qlo + ((size_t)th*N_NODES + n)*16);
      dh[0]=hb.v[0]; dh[1]=hb.v[1]; dl[0]=lb.v[0]; dl[1]=lb.v[1]; }

    // ---- K ----
    #pragma unroll
    for (int i = 0; i < 4; ++i) { float4 f = *(const float4*)(kin + ibase + 4*i);
        x[4*i]=f.x; x[4*i+1]=f.y; x[4*i+2]=f.z; x[4*i+3]=f.w; }
    #pragma unroll
    for (int e = 0; e < 16; ++e) { float a = 0.f;
        #pragma unroll
        for (int d = 0; d < 16; ++d) a = fmaf(x[d], sWk[e*16+d], a);
        y[e] = a; }
    #pragma unroll
    for (int e = 0; e < 16; ++e) { unsigned short h = bf16_rne(y[e]);
        hb.u[e] = h; lb.u[e] = bf16_rne(y[e] - bf16_tof(h)); }
    { uint4* dh = (uint4*)(khi + ((size_t)th*N_NODES + n)*16);
      uint4* dl = (uint4*)(klo + ((size_t)th*N_NODES + n)*16);
      dh[0]=hb.v[0]; dh[1]=hb.v[1]; dl[0]=lb.v[0]; dl[1]=lb.v[1]; }

    // ---- V (transposed store) ----
    #pragma unroll
    for (int i = 0; i < 4; ++i) { float4 f = *(const float4*)(vin + ibase + 4*i);
        x[4*i]=f.x; x[4*i+1]=f.y; x[4*i+2]=f.z; x[4*i+3]=f.w; }
    #pragma unroll
    for (int e = 0; e < 16; ++e) { float a = 0.f;
        #pragma unroll
        for (int d = 0; d < 16; ++d) a = fmaf(x[d], sWv[e*16+d], a);
        y[e] = a; }
    #pragma unroll
    for (int e = 0; e < 16; ++e) {
        unsigned short h = bf16_rne(y[e]);
        vthi[((size_t)th*16 + e)*N_NODES + n] = h;
        vtlo[((size_t)th*16 + e)*N_NODES + n] = bf16_rne(y[e] - bf16_tof(h));
    }
}

// ---------------------------------------------------------------------------
// Kernel 2: MFMA flash attention over the node axis.
// Block = 256 thr (4 waves), one (t,h,q-tile-of-64); wave owns 16 q-rows.
// Grid 1D: bid = qb*144 + (t*4+h)  ->  all 16 q-blocks of a (t,h) share an XCD.
// S = [qhi|qlo]x[khi|khi] + [qhi|qlo]x[klo|0]  (two 16x16x32 MFMAs, ~exact)
// P: bf16 via wave-private LDS C->A layout roundtrip; V: hi+lo split MFMAs.
// ---------------------------------------------------------------------------
__global__ __launch_bounds__(256, 4) void attn_mfma_kernel(
    const unsigned short* __restrict__ qhi, const unsigned short* __restrict__ qlo,
    const unsigned short* __restrict__ khi, const unsigned short* __restrict__ klo,
    const unsigned short* __restrict__ vthi, const unsigned short* __restrict__ vtlo,
    float* __restrict__ ob)
{
    __shared__ unsigned short khi_s[KTILE * KSTR2];
    __shared__ unsigned short klo_s[KTILE * KSTR2];
    __shared__ unsigned short vthi_s[16 * VTSTR];
    __shared__ unsigned short vtlo_s[16 * VTSTR];
    __shared__ unsigned short p_s[4][16 * PSTR2];   // per-wave private

    const int tid  = threadIdx.x;
    const int wave = tid >> 6, lane = tid & 63;
    const int m    = lane & 15, quad = lane >> 4;

    const int bid = blockIdx.x;
    const int th  = bid % 144;          // 144 = 18*8 -> th mod 8 == bid mod 8 (XCD-stable)
    const int qb  = bid / 144;
    const int t   = th >> 2, h = th & 3;
    const int q0  = qb * 64;
    const size_t base_th = (size_t)th * N_NODES;

    // ---- Q A-fragment: A[m][k], k=quad*8+j; quads 0,1 = qhi d0-7/d8-15; 2,3 = qlo ----
    const int qrow = q0 + wave * 16 + m;
    bf16x8 aq = *(const bf16x8*)((quad < 2 ? qhi : qlo) + (base_th + qrow) * 16 + (quad & 1) * 8);

    f32x4 o = {0.f, 0.f, 0.f, 0.f};
    float mrun[4] = {-INFINITY, -INFINITY, -INFINITY, -INFINITY};
    float lrun[4] = {0.f, 0.f, 0.f, 0.f};
    const bf16x8 bzero = {};

    for (int kt = 0; kt < N_NODES; kt += KTILE) {
        __syncthreads();     // previous tile's K/VT readers done
        // ---- stage K rows + V^T rows (coalesced global, padded LDS) ----
        if (tid < 128) {
            const int r = tid;
            const uint4* gh = (const uint4*)(khi + (base_th + kt + r) * 16);
            const uint4* gl = (const uint4*)(klo + (base_th + kt + r) * 16);
            uint4 a0 = gh[0], a1 = gh[1], b0 = gl[0], b1 = gl[1];
            *(uint4*)&khi_s[r * KSTR2]     = a0;
            *(uint4*)&khi_s[r * KSTR2 + 8] = a1;
            *(uint4*)&klo_s[r * KSTR2]     = b0;
            *(uint4*)&klo_s[r * KSTR2 + 8] = b1;
        } else {
            const int j = tid - 128;
            const int sel = j >> 6, d = (j >> 2) & 15, part = j & 3;
            const uint4* g = (const uint4*)((sel ? vtlo : vthi) + (base_th * 16 / N_NODES * 0 + ((size_t)th * 16 + d) * N_NODES) + kt + part * 32);
            unsigned short* dst = (sel ? vtlo_s : vthi_s) + d * VTSTR + part * 32;
            uint4 a0 = g[0], a1 = g[1], a2 = g[2], a3 = g[3];
            ((uint4*)dst)[0] = a0; ((uint4*)dst)[1] = a1;
            ((uint4*)dst)[2] = a2; ((uint4*)dst)[3] = a3;
        }
        __syncthreads();

        // ---- S = Q.K^T  (8 j-tiles of 16 nodes; 2 MFMAs each) ----
        f32x4 s[8];
        #pragma unroll
        for (int j = 0; j < 8; ++j) {
            const int krow = (j * 16 + m) * KSTR2 + (quad & 1) * 8;
            bf16x8 b1 = *(const bf16x8*)&khi_s[krow];
            bf16x8 b2 = (quad < 2) ? *(const bf16x8*)&klo_s[krow] : bzero;
            f32x4 acc = MFMA_16x16x32_BF16(aq, b1, (f32x4){0.f,0.f,0.f,0.f}, 0, 0, 0);
            s[j] = MFMA_16x16x32_BF16(aq, b2, acc, 0, 0, 0);
        }

        // ---- online softmax (exp2 domain; scale pre-folded into Q) ----
        float mx[4];
        #pragma unroll
        for (int r = 0; r < 4; ++r) {
            float v = s[0][r];
            #pragma unroll
            for (int j = 1; j < 8; ++j) v = fmaxf(v, s[j][r]);
            mx[r] = v;
        }
        #pragma unroll
        for (int mask = 1; mask < 16; mask <<= 1) {
            #pragma unroll
            for (int r = 0; r < 4; ++r) mx[r] = fmaxf(mx[r], __shfl_xor(mx[r], mask));
        }
        float alpha[4], lsum[4];
        #pragma unroll
        for (int r = 0; r < 4; ++r) {
            float mnew = fmaxf(mrun[r], mx[r]);
            alpha[r] = exp2f(mrun[r] - mnew);
            mrun[r] = mnew;
            lsum[r] = 0.f;
        }
        #pragma unroll
        for (int j = 0; j < 8; ++j) {
            #pragma unroll
            for (int r = 0; r < 4; ++r) {
                float p = exp2f(s[j][r] - mrun[r]);
                lsum[r] += p;
                p_s[wave][(quad * 4 + r) * PSTR2 + j * 16 + m] = bf16_rne(p);
            }
        }
        #pragma unroll
        for (int mask = 1; mask < 16; mask <<= 1) {
            #pragma unroll
            for (int r = 0; r < 4; ++r) lsum[r] += __shfl_xor(lsum[r], mask);
        }
        #pragma unroll
        for (int r = 0; r < 4; ++r) {
            lrun[r] = lrun[r] * alpha[r] + lsum[r];
            o[r] *= alpha[r];
        }

        // ---- O += P.V (4 chunks of 32 nodes; V hi+lo split) ----
        #pragma unroll
        for (int c = 0; c < 4; ++c) {
            bf16x8 ap  = *(const bf16x8*)&p_s[wave][m * PSTR2 + c * 32 + quad * 8];
            bf16x8 bvh = *(const bf16x8*)&vthi_s[m * VTSTR + c * 32 + quad * 8];
            bf16x8 bvl = *(const bf16x8*)&vtlo_s[m * VTSTR + c * 32 + quad * 8];
            o = MFMA_16x16x32_BF16(ap, bvh, o, 0, 0, 0);
            o = MFMA_16x16x32_BF16(ap, bvl, o, 0, 0, 0);
        }
    }

    // ---- epilogue: normalize, store obuf [n][t][64] fp32 ----
    #pragma unroll
    for (int r = 0; r < 4; ++r) {
        const int row = q0 + wave * 16 + quad * 4 + r;
        ob[((size_t)row * T_STEPS + t) * 64 + h * 16 + m] = o[r] / lrun[r];
    }
}

// ---------------------------------------------------------------------------
// Kernel 3: out[p][j] = sum_e ob[p][e] * Wo[j][e] + bo[j]   (unchanged)
// ---------------------------------------------------------------------------
__global__ __launch_bounds__(256) void outproj_kernel(
    const float* __restrict__ ob, const float* __restrict__ Wo, const float* __restrict__ bo,
    float* __restrict__ out)
{
    __shared__ float sW[64*64];
    __shared__ float sb[64];
    const int tid = threadIdx.x;
    #pragma unroll
    for (int i = 0; i < 16; ++i) sW[tid + 256*i] = Wo[tid + 256*i];
    if (tid < 64) sb[tid] = bo[tid];
    __syncthreads();

    const int p = blockIdx.x * 256 + tid;
    float r[64];
    const float4* src = (const float4*)(ob + (size_t)p * 64);
    #pragma unroll
    for (int i = 0; i < 16; ++i) {
        float4 v = src[i];
        r[4*i+0] = v.x; r[4*i+1] = v.y; r[4*i+2] = v.z; r[4*i+3] = v.w;
    }
    float4* dst = (float4*)(out + (size_t)p * 64);
    #pragma unroll 2
    for (int j4 = 0; j4 < 16; ++j4) {
        float acc0 = sb[j4*4+0], acc1 = sb[j4*4+1], acc2 = sb[j4*4+2], acc3 = sb[j4*4+3];
        #pragma unroll
        for (int e = 0; e < 64; e += 4) {
            const float4 w0 = *(const float4*)&sW[(j4*4+0)*64 + e];
            const float4 w1 = *(const float4*)&sW[(j4*4+1)*64 + e];
            const float4 w2 = *(const float4*)&sW[(j4*4+2)*64 + e];
            const float4 w3 = *(const float4*)&sW[(j4*4+3)*64 + e];
            acc0 = fmaf(r[e+0], w0.x, acc0); acc0 = fmaf(r[e+1], w0.y, acc0);
            acc0 = fmaf(r[e+2], w0.z, acc0); acc0 = fmaf(r[e+3], w0.w, acc0);
            acc1 = fmaf(r[e+0], w1.x, acc1); acc1 = fmaf(r[e+1], w1.y, acc1);
            acc1 = fmaf(r[e+2], w1.z, acc1); acc1 = fmaf(r[e+3], w1.w, acc1);
            acc2 = fmaf(r[e+0], w2.x, acc2); acc2 = fmaf(r[e+1], w2.y, acc2);
            acc2 = fmaf(r[e+2], w2.z, acc2); acc2 = fmaf(r[e+3], w2.w, acc2);
            acc3 = fmaf(r[e+0], w3.x, acc3); acc3 = fmaf(r[e+1], w3.y, acc3);
            acc3 = fmaf(r[e+2], w3.z, acc3); acc3 = fmaf(r[e+3], w3.w, acc3);
        }
        dst[j4] = make_float4(acc0, acc1, acc2, acc3);
    }
}

// ---------------------------------------------------------------------------
extern "C" void kernel_launch(void* const* d_in, const int* in_sizes, int n_in,
                              void* d_out, int out_size, void* d_ws, size_t ws_size,
                              hipStream_t stream)
{
    (void)in_sizes; (void)n_in; (void)out_size; (void)ws_size;
    const float* values = (const float*)d_in[0];
    const float* keys   = (const float*)d_in[1];
    const float* query  = (const float*)d_in[2];
    const float* Wv     = (const float*)d_in[3];
    const float* Wk     = (const float*)d_in[4];
    const float* Wq     = (const float*)d_in[5];
    const float* Wo     = (const float*)d_in[6];
    const float* bo     = (const float*)d_in[7];

    const size_t PLANE = (size_t)T_STEPS * N_NODES * 16;   // 589,824 elems per (t,h,*) plane... x4 th = 2,359,296
    const size_t TOT   = (size_t)144 * N_NODES * 16;       // 2,359,296 bf16 elems per tensor
    unsigned short* ws16 = (unsigned short*)d_ws;
    unsigned short* qhi  = ws16;
    unsigned short* qlo  = ws16 + 1*TOT;
    unsigned short* khi  = ws16 + 2*TOT;
    unsigned short* klo  = ws16 + 3*TOT;
    unsigned short* vthi = ws16 + 4*TOT;
    unsigned short* vtlo = ws16 + 5*TOT;
    float* obuf = (float*)(ws16 + 6*TOT);                  // 9.4 MB fp32; total ws = 37.75 MB
    (void)PLANE;

    proj2_kernel<<<dim3(16, 36), 256, 0, stream>>>(values, keys, query, Wv, Wk, Wq,
                                                   qhi, qlo, khi, klo, vthi, vtlo);
    attn_mfma_kernel<<<dim3(16 * 144), 256, 0, stream>>>(qhi, qlo, khi, klo, vthi, vtlo, obuf);
    outproj_kernel<<<dim3(144), 256, 0, stream>>>(obuf, Wo, bo, (float*)d_out);
}

// Round 3
// 187.697 us; speedup vs baseline: 1.6217x; 1.1112x over previous
//
#include <hip/hip_runtime.h>
#include <math.h>

#define N_NODES 1024
#define T_STEPS 36
#define KTILE   128          // k-nodes per attn LDS tile
#define KSTR2   24           // K LDS row stride (bf16): 16 data + 8 pad; phase-bank 2-way (free)
#define VTSTR   136          // V^T LDS row stride (bf16): 128 data + 8 pad; 272B = 16B-mult
#define PSTR3   136          // P LDS row stride (bf16): 272B rows -> b64 writes / b128 reads aligned, 2-way max
#define WOS     72           // outproj Wo LDS stride (bf16): 144B rows, 16B-mult
#define OBS2    72           // outproj ob-tile LDS stride (bf16)

typedef __bf16  bf16x8 __attribute__((ext_vector_type(8)));
typedef float   f32x4  __attribute__((ext_vector_type(4)));

#define MFMA_BF16 __builtin_amdgcn_mfma_f32_16x16x32_bf16

__device__ __forceinline__ unsigned short bf16_rne(float f) {
    unsigned int u = __float_as_uint(f);
    u += 0x7FFFu + ((u >> 16) & 1u);
    return (unsigned short)(u >> 16);
}
__device__ __forceinline__ float bf16_tof(unsigned short h) {
    return __uint_as_float(((unsigned int)h) << 16);
}
// two fp32 -> packed bf16x2 dword (RNE), low half = a
__device__ __forceinline__ unsigned int pack_bf16_2(float a, float b) {
    unsigned int ua = __float_as_uint(a); ua += 0x7FFFu + ((ua >> 16) & 1u);
    unsigned int ub = __float_as_uint(b); ub += 0x7FFFu + ((ub >> 16) & 1u);
    return (ua >> 16) | (ub & 0xFFFF0000u);
}

// ---------------------------------------------------------------------------
// Kernel 1: projections, one thread per node. Coalesced outputs:
//   qhi/qlo, khi/klo : [t][h][n][16]  (q pre-scaled by log2(e)/8)
//   vthi/vtlo        : [t][h][d][n]   (scalar b16 stores, lanes = consecutive n)
// ---------------------------------------------------------------------------
__global__ __launch_bounds__(128) void proj3_kernel(
    const float* __restrict__ vin, const float* __restrict__ kin, const float* __restrict__ qin,
    const float* __restrict__ Wv, const float* __restrict__ Wk, const float* __restrict__ Wq,
    unsigned short* __restrict__ qhi, unsigned short* __restrict__ qlo,
    unsigned short* __restrict__ khi, unsigned short* __restrict__ klo,
    unsigned short* __restrict__ vthi, unsigned short* __restrict__ vtlo)
{
    __shared__ float sWv[256], sWk[256], sWq[256];
    const int tid = threadIdx.x;
    sWv[tid] = Wv[tid]; sWv[tid+128] = Wv[tid+128];
    sWk[tid] = Wk[tid]; sWk[tid+128] = Wk[tid+128];
    sWq[tid] = Wq[tid]; sWq[tid+128] = Wq[tid+128];
    __syncthreads();

    const int t = blockIdx.y;
    const int n = blockIdx.x * 128 + tid;
    const size_t ib = ((size_t)n * T_STEPS + t) * 64;
    const float QSCALE = 0.18033688011112042f;   // log2(e)/sqrt(64)

    float x[64];

    // ---- Q ----
    #pragma unroll
    for (int i = 0; i < 16; ++i) { float4 f = *(const float4*)(qin + ib + 4*i);
        x[4*i]=f.x; x[4*i+1]=f.y; x[4*i+2]=f.z; x[4*i+3]=f.w; }
    #pragma unroll
    for (int hd = 0; hd < 4; ++hd) {
        union { unsigned short u[16]; uint4 v[2]; } hb, lb;
        #pragma unroll
        for (int e = 0; e < 16; ++e) {
            float a = 0.f;
            #pragma unroll
            for (int d = 0; d < 16; ++d) a = fmaf(x[hd*16+d], sWq[e*16+d], a);
            a *= QSCALE;
            unsigned short hh = bf16_rne(a);
            hb.u[e] = hh; lb.u[e] = bf16_rne(a - bf16_tof(hh));
        }
        uint4* dh = (uint4*)(qhi + ((size_t)(t*4+hd)*N_NODES + n)*16);
        uint4* dl = (uint4*)(qlo + ((size_t)(t*4+hd)*N_NODES + n)*16);
        dh[0]=hb.v[0]; dh[1]=hb.v[1]; dl[0]=lb.v[0]; dl[1]=lb.v[1];
    }

    // ---- K ----
    #pragma unroll
    for (int i = 0; i < 16; ++i) { float4 f = *(const float4*)(kin + ib + 4*i);
        x[4*i]=f.x; x[4*i+1]=f.y; x[4*i+2]=f.z; x[4*i+3]=f.w; }
    #pragma unroll
    for (int hd = 0; hd < 4; ++hd) {
        union { unsigned short u[16]; uint4 v[2]; } hb, lb;
        #pragma unroll
        for (int e = 0; e < 16; ++e) {
            float a = 0.f;
            #pragma unroll
            for (int d = 0; d < 16; ++d) a = fmaf(x[hd*16+d], sWk[e*16+d], a);
            unsigned short hh = bf16_rne(a);
            hb.u[e] = hh; lb.u[e] = bf16_rne(a - bf16_tof(hh));
        }
        uint4* dh = (uint4*)(khi + ((size_t)(t*4+hd)*N_NODES + n)*16);
        uint4* dl = (uint4*)(klo + ((size_t)(t*4+hd)*N_NODES + n)*16);
        dh[0]=hb.v[0]; dh[1]=hb.v[1]; dl[0]=lb.v[0]; dl[1]=lb.v[1];
    }

    // ---- V (transposed planes; lanes write consecutive n -> coalesced) ----
    #pragma unroll
    for (int i = 0; i < 16; ++i) { float4 f = *(const float4*)(vin + ib + 4*i);
        x[4*i]=f.x; x[4*i+1]=f.y; x[4*i+2]=f.z; x[4*i+3]=f.w; }
    #pragma unroll
    for (int hd = 0; hd < 4; ++hd) {
        #pragma unroll
        for (int e = 0; e < 16; ++e) {
            float a = 0.f;
            #pragma unroll
            for (int d = 0; d < 16; ++d) a = fmaf(x[hd*16+d], sWv[e*16+d], a);
            unsigned short hh = bf16_rne(a);
            const size_t off = ((size_t)(t*4+hd)*16 + e)*N_NODES + n;
            vthi[off] = hh;
            vtlo[off] = bf16_rne(a - bf16_tof(hh));
        }
    }
}

// ---------------------------------------------------------------------------
// Kernel 2: MFMA flash attention, S computed transposed (A=K, B=Q-in-regs).
// Fixed-shift softmax (max==0): p=exp2(s), no per-tile reductions.
// Lane's 4 S-values = 4 consecutive nodes of P-row m -> one ds_write_b64.
// PV: A=P rows (b128), B=V^T (b128, hi+lo split). C-layout: row=qrow, col=d.
// ---------------------------------------------------------------------------
__global__ __launch_bounds__(256, 4) void attn_mfma2_kernel(
    const unsigned short* __restrict__ qhi, const unsigned short* __restrict__ qlo,
    const unsigned short* __restrict__ khi, const unsigned short* __restrict__ klo,
    const unsigned short* __restrict__ vthi, const unsigned short* __restrict__ vtlo,
    unsigned short* __restrict__ obh, unsigned short* __restrict__ obl)
{
    __shared__ unsigned short khi_s[KTILE * KSTR2];
    __shared__ unsigned short klo_s[KTILE * KSTR2];
    __shared__ unsigned short vthi_s[16 * VTSTR];
    __shared__ unsigned short vtlo_s[16 * VTSTR];
    __shared__ unsigned short p_s[4][16 * PSTR3];   // per-wave private (no barrier)

    const int tid  = threadIdx.x;
    const int wave = tid >> 6, lane = tid & 63;
    const int m = lane & 15, quad = lane >> 4;

    const int bid = blockIdx.x;
    const int th  = bid % 144;          // th mod 8 stable per (t,h) -> XCD-local K/V reuse
    const int qb  = bid / 144;
    const int t   = th >> 2, hd = th & 3;
    const int q0  = qb * 64;
    const size_t base_th = (size_t)th * N_NODES;

    // Q as B-operand, resident in registers for the whole kernel.
    // B1 = [Qh|Qh] (k 0..31), B2 = [Ql|0] ; A = [Kh|Kl] per tile.
    const int qrow = q0 + wave * 16 + m;
    const bf16x8 bzero = {};
    const bf16x8 b1q = *(const bf16x8*)(qhi + (base_th + qrow) * 16 + (quad & 1) * 8);
    const bf16x8 b2q = (quad < 2)
        ? *(const bf16x8*)(qlo + (base_th + qrow) * 16 + (quad & 1) * 8) : bzero;

    f32x4 o = {0.f, 0.f, 0.f, 0.f};
    float lsum = 0.f;
    unsigned short* pw = &p_s[wave][0];
    const unsigned short* kbase = (quad < 2) ? khi_s : klo_s;

    for (int kt = 0; kt < N_NODES; kt += KTILE) {
        __syncthreads();
        if (tid < 128) {                 // stage K hi/lo rows
            const int r = tid;
            const uint4* gh = (const uint4*)(khi + (base_th + kt + r) * 16);
            const uint4* gl = (const uint4*)(klo + (base_th + kt + r) * 16);
            uint4 a0 = gh[0], a1 = gh[1], c0 = gl[0], c1 = gl[1];
            *(uint4*)&khi_s[r * KSTR2]     = a0;
            *(uint4*)&khi_s[r * KSTR2 + 8] = a1;
            *(uint4*)&klo_s[r * KSTR2]     = c0;
            *(uint4*)&klo_s[r * KSTR2 + 8] = c1;
        } else {                         // stage V^T hi/lo rows
            const int j = tid - 128;
            const int sel = j >> 6, d = (j >> 2) & 15, part = j & 3;
            const unsigned short* src = (sel ? vtlo : vthi)
                + ((size_t)th * 16 + d) * N_NODES + kt + part * 32;
            unsigned short* dst = (sel ? vtlo_s : vthi_s) + d * VTSTR + part * 32;
            uint4 a0 = ((const uint4*)src)[0], a1 = ((const uint4*)src)[1];
            uint4 a2 = ((const uint4*)src)[2], a3 = ((const uint4*)src)[3];
            ((uint4*)dst)[0] = a0; ((uint4*)dst)[1] = a1;
            ((uint4*)dst)[2] = a2; ((uint4*)dst)[3] = a3;
        }
        __syncthreads();

        // ---- S^T tiles + exp2 + packed P store ----
        #pragma unroll
        for (int j = 0; j < 8; ++j) {
            bf16x8 a = *(const bf16x8*)(kbase + (j * 16 + m) * KSTR2 + (quad & 1) * 8);
            f32x4 s = MFMA_BF16(a, b1q, (f32x4){0.f, 0.f, 0.f, 0.f}, 0, 0, 0);
            s = MFMA_BF16(a, b2q, s, 0, 0, 0);
            float p0 = exp2f(s[0]), p1 = exp2f(s[1]);
            float p2 = exp2f(s[2]), p3 = exp2f(s[3]);
            lsum += (p0 + p1) + (p2 + p3);
            uint2 pk;
            pk.x = pack_bf16_2(p0, p1);
            pk.y = pack_bf16_2(p2, p3);
            *(uint2*)(pw + m * PSTR3 + j * 16 + quad * 4) = pk;   // P[qrow=m][4 nodes]
        }

        // ---- O += P.V (4 chunks of 32 nodes; V hi+lo) ----
        #pragma unroll
        for (int c = 0; c < 4; ++c) {
            bf16x8 ap = *(const bf16x8*)(pw + m * PSTR3 + c * 32 + quad * 8);
            bf16x8 vh = *(const bf16x8*)&vthi_s[m * VTSTR + c * 32 + quad * 8];
            bf16x8 vl = *(const bf16x8*)&vtlo_s[m * VTSTR + c * 32 + quad * 8];
            o = MFMA_BF16(ap, vh, o, 0, 0, 0);
            o = MFMA_BF16(ap, vl, o, 0, 0, 0);
        }
    }

    // ---- finalize: reduce l across quads, fetch per-row l, store bf16 hi/lo ----
    lsum += __shfl_xor(lsum, 16);
    lsum += __shfl_xor(lsum, 32);        // lane(q,m) now holds full l for qrow m
    #pragma unroll
    for (int r = 0; r < 4; ++r) {
        const float l = __shfl(lsum, quad * 4 + r);       // l for this lane's C-row
        const float val = o[r] / l;
        const int row = q0 + wave * 16 + quad * 4 + r;
        const size_t off = ((size_t)row * T_STEPS + t) * 64 + hd * 16 + m;
        unsigned short hh = bf16_rne(val);
        obh[off] = hh;
        obl[off] = bf16_rne(val - bf16_tof(hh));
    }
}

// ---------------------------------------------------------------------------
// Kernel 3: MFMA output projection. out = ob @ Wo^T + bo, hi/lo split both
// operands (3-term product; dropped lo*lo ~ 2^-16 rel).
// ---------------------------------------------------------------------------
__global__ __launch_bounds__(256) void outproj_mfma_kernel(
    const unsigned short* __restrict__ obh, const unsigned short* __restrict__ obl,
    const float* __restrict__ Wo, const float* __restrict__ bo,
    float* __restrict__ out)
{
    __shared__ unsigned short woh[64 * WOS], wol[64 * WOS];
    __shared__ unsigned short oth[64 * OBS2], otl[64 * OBS2];
    __shared__ float sb[64];
    const int tid = threadIdx.x;

    #pragma unroll
    for (int i = 0; i < 16; ++i) {       // stage + split Wo
        int idx = tid + 256 * i;
        int r = idx >> 6, c = idx & 63;
        float w = Wo[idx];
        unsigned short hh = bf16_rne(w);
        woh[r * WOS + c] = hh;
        wol[r * WOS + c] = bf16_rne(w - bf16_tof(hh));
    }
    if (tid < 64) sb[tid] = bo[tid];

    const size_t p0 = (size_t)blockIdx.x * 64;
    #pragma unroll
    for (int i = 0; i < 2; ++i) {        // stage ob tile (bf16 planes)
        int idx = tid + 256 * i;         // uint4 id, 512 total per plane
        int r = idx >> 3, c = (idx & 7) * 8;
        *(uint4*)&oth[r * OBS2 + c] = *(const uint4*)(obh + (p0 + r) * 64 + c);
        *(uint4*)&otl[r * OBS2 + c] = *(const uint4*)(obl + (p0 + r) * 64 + c);
    }
    __syncthreads();

    const int wave = tid >> 6, lane = tid & 63;
    const int m = lane & 15, quad = lane >> 4;
    const int r0 = wave * 16;

    bf16x8 ah[2], al[2];
    #pragma unroll
    for (int kh = 0; kh < 2; ++kh) {
        ah[kh] = *(const bf16x8*)&oth[(r0 + m) * OBS2 + kh * 32 + quad * 8];
        al[kh] = *(const bf16x8*)&otl[(r0 + m) * OBS2 + kh * 32 + quad * 8];
    }

    f32x4 acc[4] = {{0,0,0,0},{0,0,0,0},{0,0,0,0},{0,0,0,0}};
    #pragma unroll
    for (int jt = 0; jt < 4; ++jt) {
        #pragma unroll
        for (int kh = 0; kh < 2; ++kh) {
            bf16x8 bh = *(const bf16x8*)&woh[(jt * 16 + m) * WOS + kh * 32 + quad * 8];
            bf16x8 bl = *(const bf16x8*)&wol[(jt * 16 + m) * WOS + kh * 32 + quad * 8];
            acc[jt] = MFMA_BF16(ah[kh], bh, acc[jt], 0, 0, 0);
            acc[jt] = MFMA_BF16(al[kh], bh, acc[jt], 0, 0, 0);
            acc[jt] = MFMA_BF16(ah[kh], bl, acc[jt], 0, 0, 0);
        }
    }

    #pragma unroll
    for (int jt = 0; jt < 4; ++jt) {
        const float b = sb[jt * 16 + m];
        #pragma unroll
        for (int r = 0; r < 4; ++r)
            out[(p0 + r0 + quad * 4 + r) * 64 + jt * 16 + m] = acc[jt][r] + b;
    }
}

// ---------------------------------------------------------------------------
extern "C" void kernel_launch(void* const* d_in, const int* in_sizes, int n_in,
                              void* d_out, int out_size, void* d_ws, size_t ws_size,
                              hipStream_t stream)
{
    (void)in_sizes; (void)n_in; (void)out_size; (void)ws_size;
    const float* values = (const float*)d_in[0];
    const float* keys   = (const float*)d_in[1];
    const float* query  = (const float*)d_in[2];
    const float* Wv     = (const float*)d_in[3];
    const float* Wk     = (const float*)d_in[4];
    const float* Wq     = (const float*)d_in[5];
    const float* Wo     = (const float*)d_in[6];
    const float* bo     = (const float*)d_in[7];

    const size_t TOT = (size_t)144 * N_NODES * 16;   // 2,359,296 bf16 per plane
    unsigned short* ws16 = (unsigned short*)d_ws;
    unsigned short* qhi  = ws16;
    unsigned short* qlo  = ws16 + 1*TOT;
    unsigned short* khi  = ws16 + 2*TOT;
    unsigned short* klo  = ws16 + 3*TOT;
    unsigned short* vthi = ws16 + 4*TOT;
    unsigned short* vtlo = ws16 + 5*TOT;
    unsigned short* obh  = ws16 + 6*TOT;
    unsigned short* obl  = ws16 + 7*TOT;             // total ws = 8*TOT*2B = 37.75 MB

    proj3_kernel<<<dim3(8, 36), 128, 0, stream>>>(values, keys, query, Wv, Wk, Wq,
                                                  qhi, qlo, khi, klo, vthi, vtlo);
    attn_mfma2_kernel<<<dim3(16 * 144), 256, 0, stream>>>(qhi, qlo, khi, klo, vthi, vtlo,
                                                          obh, obl);
    outproj_mfma_kernel<<<dim3(576), 256, 0, stream>>>(obh, obl, Wo, bo, (float*)d_out);
}

// Round 4
// 156.271 us; speedup vs baseline: 1.9478x; 1.2011x over previous
//
#include <hip/hip_runtime.h>
#include <math.h>

#define N_NODES 1024
#define T_STEPS 36
#define KTILE   128          // k-nodes per attn LDS tile
#define KSTR2   24           // K LDS row stride (bf16): 16 data + 8 pad; b128 reads 4-deep/bank (min)
#define VTSTR   136          // V^T LDS row stride (bf16): 128 data + 8 pad; b128 reads 8-deep (min)
#define WOS     72           // outproj Wo LDS stride (bf16)
#define OBS2    72           // outproj ob-tile LDS stride (bf16)

typedef __bf16  bf16x8 __attribute__((ext_vector_type(8)));
typedef float   f32x4  __attribute__((ext_vector_type(4)));

#define MFMA_BF16 __builtin_amdgcn_mfma_f32_16x16x32_bf16

__device__ __forceinline__ unsigned short bf16_rne(float f) {
    unsigned int u = __float_as_uint(f);
    u += 0x7FFFu + ((u >> 16) & 1u);
    return (unsigned short)(u >> 16);
}
__device__ __forceinline__ float bf16_tof(unsigned short h) {
    return __uint_as_float(((unsigned int)h) << 16);
}
// RNE-biased uint of fp32 (upper 16 bits = rounded bf16)
__device__ __forceinline__ unsigned int bf16_bias(float f) {
    unsigned int u = __float_as_uint(f);
    return u + 0x7FFFu + ((u >> 16) & 1u);
}

// ---------------------------------------------------------------------------
// Kernel 1: projections, one thread per (n,t) row. W row loaded once into
// registers per output element, reused across the 4 heads (16 FMA / b128).
//   qhi/qlo, khi/klo : [t][h][n][16]  (q pre-scaled by log2(e)/8)
//   vthi/vtlo        : [t][h][d][n]   (lanes = consecutive n -> coalesced)
// ---------------------------------------------------------------------------
__global__ __launch_bounds__(128) void proj4_kernel(
    const float* __restrict__ vin, const float* __restrict__ kin, const float* __restrict__ qin,
    const float* __restrict__ Wv, const float* __restrict__ Wk, const float* __restrict__ Wq,
    unsigned short* __restrict__ qhi, unsigned short* __restrict__ qlo,
    unsigned short* __restrict__ khi, unsigned short* __restrict__ klo,
    unsigned short* __restrict__ vthi, unsigned short* __restrict__ vtlo)
{
    __shared__ float sWv[256], sWk[256], sWq[256];
    const int tid = threadIdx.x;
    sWv[tid] = Wv[tid]; sWv[tid+128] = Wv[tid+128];
    sWk[tid] = Wk[tid]; sWk[tid+128] = Wk[tid+128];
    sWq[tid] = Wq[tid]; sWq[tid+128] = Wq[tid+128];
    __syncthreads();

    const int t = blockIdx.y;
    const int n = blockIdx.x * 128 + tid;
    const size_t ib = ((size_t)n * T_STEPS + t) * 64;
    const float QSCALE = 0.18033688011112042f;   // log2(e)/sqrt(64)

    float x[64], y[4][16];

    // ---- Q ----
    #pragma unroll
    for (int i = 0; i < 16; ++i) { float4 f = *(const float4*)(qin + ib + 4*i);
        x[4*i]=f.x; x[4*i+1]=f.y; x[4*i+2]=f.z; x[4*i+3]=f.w; }
    #pragma unroll
    for (int e = 0; e < 16; ++e) {
        float4 w0 = *(const float4*)&sWq[e*16+0],  w1 = *(const float4*)&sWq[e*16+4];
        float4 w2 = *(const float4*)&sWq[e*16+8],  w3 = *(const float4*)&sWq[e*16+12];
        #pragma unroll
        for (int hd = 0; hd < 4; ++hd) {
            const float* xr = &x[hd*16];
            float a = xr[0]*w0.x;
            a = fmaf(xr[1],w0.y,a);  a = fmaf(xr[2],w0.z,a);  a = fmaf(xr[3],w0.w,a);
            a = fmaf(xr[4],w1.x,a);  a = fmaf(xr[5],w1.y,a);  a = fmaf(xr[6],w1.z,a);  a = fmaf(xr[7],w1.w,a);
            a = fmaf(xr[8],w2.x,a);  a = fmaf(xr[9],w2.y,a);  a = fmaf(xr[10],w2.z,a); a = fmaf(xr[11],w2.w,a);
            a = fmaf(xr[12],w3.x,a); a = fmaf(xr[13],w3.y,a); a = fmaf(xr[14],w3.z,a); a = fmaf(xr[15],w3.w,a);
            y[hd][e] = a * QSCALE;
        }
    }
    #pragma unroll
    for (int hd = 0; hd < 4; ++hd) {
        union { unsigned short u[16]; uint4 v[2]; } hb, lb;
        #pragma unroll
        for (int e = 0; e < 16; ++e) { unsigned short hh = bf16_rne(y[hd][e]);
            hb.u[e] = hh; lb.u[e] = bf16_rne(y[hd][e] - bf16_tof(hh)); }
        uint4* dh = (uint4*)(qhi + ((size_t)(t*4+hd)*N_NODES + n)*16);
        uint4* dl = (uint4*)(qlo + ((size_t)(t*4+hd)*N_NODES + n)*16);
        dh[0]=hb.v[0]; dh[1]=hb.v[1]; dl[0]=lb.v[0]; dl[1]=lb.v[1];
    }

    // ---- K ----
    #pragma unroll
    for (int i = 0; i < 16; ++i) { float4 f = *(const float4*)(kin + ib + 4*i);
        x[4*i]=f.x; x[4*i+1]=f.y; x[4*i+2]=f.z; x[4*i+3]=f.w; }
    #pragma unroll
    for (int e = 0; e < 16; ++e) {
        float4 w0 = *(const float4*)&sWk[e*16+0],  w1 = *(const float4*)&sWk[e*16+4];
        float4 w2 = *(const float4*)&sWk[e*16+8],  w3 = *(const float4*)&sWk[e*16+12];
        #pragma unroll
        for (int hd = 0; hd < 4; ++hd) {
            const float* xr = &x[hd*16];
            float a = xr[0]*w0.x;
            a = fmaf(xr[1],w0.y,a);  a = fmaf(xr[2],w0.z,a);  a = fmaf(xr[3],w0.w,a);
            a = fmaf(xr[4],w1.x,a);  a = fmaf(xr[5],w1.y,a);  a = fmaf(xr[6],w1.z,a);  a = fmaf(xr[7],w1.w,a);
            a = fmaf(xr[8],w2.x,a);  a = fmaf(xr[9],w2.y,a);  a = fmaf(xr[10],w2.z,a); a = fmaf(xr[11],w2.w,a);
            a = fmaf(xr[12],w3.x,a); a = fmaf(xr[13],w3.y,a); a = fmaf(xr[14],w3.z,a); a = fmaf(xr[15],w3.w,a);
            y[hd][e] = a;
        }
    }
    #pragma unroll
    for (int hd = 0; hd < 4; ++hd) {
        union { unsigned short u[16]; uint4 v[2]; } hb, lb;
        #pragma unroll
        for (int e = 0; e < 16; ++e) { unsigned short hh = bf16_rne(y[hd][e]);
            hb.u[e] = hh; lb.u[e] = bf16_rne(y[hd][e] - bf16_tof(hh)); }
        uint4* dh = (uint4*)(khi + ((size_t)(t*4+hd)*N_NODES + n)*16);
        uint4* dl = (uint4*)(klo + ((size_t)(t*4+hd)*N_NODES + n)*16);
        dh[0]=hb.v[0]; dh[1]=hb.v[1]; dl[0]=lb.v[0]; dl[1]=lb.v[1];
    }

    // ---- V (transposed planes) ----
    #pragma unroll
    for (int i = 0; i < 16; ++i) { float4 f = *(const float4*)(vin + ib + 4*i);
        x[4*i]=f.x; x[4*i+1]=f.y; x[4*i+2]=f.z; x[4*i+3]=f.w; }
    #pragma unroll
    for (int e = 0; e < 16; ++e) {
        float4 w0 = *(const float4*)&sWv[e*16+0],  w1 = *(const float4*)&sWv[e*16+4];
        float4 w2 = *(const float4*)&sWv[e*16+8],  w3 = *(const float4*)&sWv[e*16+12];
        #pragma unroll
        for (int hd = 0; hd < 4; ++hd) {
            const float* xr = &x[hd*16];
            float a = xr[0]*w0.x;
            a = fmaf(xr[1],w0.y,a);  a = fmaf(xr[2],w0.z,a);  a = fmaf(xr[3],w0.w,a);
            a = fmaf(xr[4],w1.x,a);  a = fmaf(xr[5],w1.y,a);  a = fmaf(xr[6],w1.z,a);  a = fmaf(xr[7],w1.w,a);
            a = fmaf(xr[8],w2.x,a);  a = fmaf(xr[9],w2.y,a);  a = fmaf(xr[10],w2.z,a); a = fmaf(xr[11],w2.w,a);
            a = fmaf(xr[12],w3.x,a); a = fmaf(xr[13],w3.y,a); a = fmaf(xr[14],w3.z,a); a = fmaf(xr[15],w3.w,a);
            unsigned short hh = bf16_rne(a);
            const size_t off = ((size_t)(t*4+hd)*16 + e)*N_NODES + n;
            vthi[off] = hh;
            vtlo[off] = bf16_rne(a - bf16_tof(hh));
        }
    }
}

// ---------------------------------------------------------------------------
// Kernel 2: MFMA flash attention — P never touches LDS.
// Block = 256 thr (4 waves), 128 q-rows; wave owns 32 q-rows (2 rowgroups of
// 16 sharing each K/V fragment read). S^T via A=K,B=Q(regs). PV k-order is
// PERMUTED (k=quad*8+jj <-> node=(jj>=4)*16+quad*4+(jj&3)) so the PV
// A-fragment is the lane's own packed exp2 results; V^T is staged in LDS in
// that same permuted node order. Fixed-shift softmax; lsum from rounded p.
// ---------------------------------------------------------------------------
__global__ __launch_bounds__(256, 4) void attn_mfma3_kernel(
    const unsigned short* __restrict__ qhi, const unsigned short* __restrict__ qlo,
    const unsigned short* __restrict__ khi, const unsigned short* __restrict__ klo,
    const unsigned short* __restrict__ vthi, const unsigned short* __restrict__ vtlo,
    unsigned short* __restrict__ obh, unsigned short* __restrict__ obl)
{
    __shared__ unsigned short khi_s[KTILE * KSTR2];
    __shared__ unsigned short klo_s[KTILE * KSTR2];
    __shared__ unsigned short vthi_s[16 * VTSTR];   // permuted node order per 32-chunk
    __shared__ unsigned short vtlo_s[16 * VTSTR];

    const int tid  = threadIdx.x;
    const int wave = tid >> 6, lane = tid & 63;
    const int m = lane & 15, quad = lane >> 4;

    const int bid = blockIdx.x;
    const int th  = bid % 144;          // th mod 8 stable per (t,h) -> XCD-local K/V reuse
    const int qb  = bid / 144;
    const int t   = th >> 2, hd = th & 3;
    const int q0  = qb * 128;
    const size_t base_th = (size_t)th * N_NODES;

    // Q as B-operand, 2 rowgroups resident in registers.
    const bf16x8 bzero = {};
    bf16x8 b1q[2], b2q[2];
    #pragma unroll
    for (int g = 0; g < 2; ++g) {
        const int qrow = q0 + wave * 32 + g * 16 + m;
        b1q[g] = *(const bf16x8*)(qhi + (base_th + qrow) * 16 + (quad & 1) * 8);
        b2q[g] = (quad < 2)
            ? *(const bf16x8*)(qlo + (base_th + qrow) * 16 + (quad & 1) * 8) : bzero;
    }

    f32x4 og[2] = {{0.f,0.f,0.f,0.f},{0.f,0.f,0.f,0.f}};
    float lsum[2] = {0.f, 0.f};
    const unsigned short* kbase = (quad < 2) ? khi_s : klo_s;
    const int koff = m * KSTR2 + (quad & 1) * 8;
    const int voff = m * VTSTR + quad * 8;

    for (int kt = 0; kt < N_NODES; kt += KTILE) {
        __syncthreads();
        if (tid < 128) {                 // stage K hi/lo rows (waves 0,1)
            const int r = tid;
            const uint4* gh = (const uint4*)(khi + (base_th + kt + r) * 16);
            const uint4* gl = (const uint4*)(klo + (base_th + kt + r) * 16);
            uint4 a0 = gh[0], a1 = gh[1], c0 = gl[0], c1 = gl[1];
            *(uint4*)&khi_s[r * KSTR2]     = a0;
            *(uint4*)&khi_s[r * KSTR2 + 8] = a1;
            *(uint4*)&klo_s[r * KSTR2]     = c0;
            *(uint4*)&klo_s[r * KSTR2 + 8] = c1;
        } else {                         // stage V^T rows permuted (waves 2,3)
            const int j = tid - 128;
            const int sel = j >> 6, d = (j >> 2) & 15, part = j & 3;
            const unsigned short* src = (sel ? vtlo : vthi)
                + ((size_t)th * 16 + d) * N_NODES + kt + part * 32;
            unsigned short* dst = (sel ? vtlo_s : vthi_s) + d * VTSTR + part * 32;
            uint4 a0 = ((const uint4*)src)[0], a1 = ((const uint4*)src)[1];
            uint4 a2 = ((const uint4*)src)[2], a3 = ((const uint4*)src)[3];
            // node n (0..31) -> pos ((n>>2)&3)*8 + (n>>4)*4 + (n&3)
            *(uint2*)&dst[0]  = make_uint2(a0.x, a0.y);   // nodes 0-3
            *(uint2*)&dst[8]  = make_uint2(a0.z, a0.w);   // nodes 4-7
            *(uint2*)&dst[16] = make_uint2(a1.x, a1.y);   // nodes 8-11
            *(uint2*)&dst[24] = make_uint2(a1.z, a1.w);   // nodes 12-15
            *(uint2*)&dst[4]  = make_uint2(a2.x, a2.y);   // nodes 16-19
            *(uint2*)&dst[12] = make_uint2(a2.z, a2.w);   // nodes 20-23
            *(uint2*)&dst[20] = make_uint2(a3.x, a3.y);   // nodes 24-27
            *(uint2*)&dst[28] = make_uint2(a3.z, a3.w);   // nodes 28-31
        }
        __syncthreads();

        #pragma unroll
        for (int c = 0; c < 4; ++c) {    // 32-node group = S-tiles 2c, 2c+1
            bf16x8 a0 = *(const bf16x8*)(kbase + (2*c    ) * 16 * KSTR2 + koff);
            bf16x8 a1 = *(const bf16x8*)(kbase + (2*c + 1) * 16 * KSTR2 + koff);
            unsigned int pk[2][4];
            #pragma unroll
            for (int g = 0; g < 2; ++g) {
                f32x4 s0 = MFMA_BF16(a0, b1q[g], (f32x4){0.f,0.f,0.f,0.f}, 0, 0, 0);
                s0 = MFMA_BF16(a0, b2q[g], s0, 0, 0, 0);
                f32x4 s1 = MFMA_BF16(a1, b1q[g], (f32x4){0.f,0.f,0.f,0.f}, 0, 0, 0);
                s1 = MFMA_BF16(a1, b2q[g], s1, 0, 0, 0);
                unsigned int u[8];
                float ls = 0.f;
                #pragma unroll
                for (int r = 0; r < 4; ++r) {
                    u[r]   = bf16_bias(__builtin_amdgcn_exp2f(s0[r]));
                    u[4+r] = bf16_bias(__builtin_amdgcn_exp2f(s1[r]));
                    ls += __uint_as_float(u[r]   & 0xFFFF0000u);
                    ls += __uint_as_float(u[4+r] & 0xFFFF0000u);
                }
                lsum[g] += ls;
                pk[g][0] = __builtin_amdgcn_perm(u[1], u[0], 0x07060302u);
                pk[g][1] = __builtin_amdgcn_perm(u[3], u[2], 0x07060302u);
                pk[g][2] = __builtin_amdgcn_perm(u[5], u[4], 0x07060302u);
                pk[g][3] = __builtin_amdgcn_perm(u[7], u[6], 0x07060302u);
            }
            bf16x8 vh = *(const bf16x8*)&vthi_s[voff + c * 32];
            bf16x8 vl = *(const bf16x8*)&vtlo_s[voff + c * 32];
            #pragma unroll
            for (int g = 0; g < 2; ++g) {
                union { unsigned int u[4]; bf16x8 v; } ap;
                ap.u[0] = pk[g][0]; ap.u[1] = pk[g][1];
                ap.u[2] = pk[g][2]; ap.u[3] = pk[g][3];
                og[g] = MFMA_BF16(ap.v, vh, og[g], 0, 0, 0);
                og[g] = MFMA_BF16(ap.v, vl, og[g], 0, 0, 0);
            }
        }
    }

    // ---- finalize: reduce l across quads, normalize, store bf16 hi/lo ----
    #pragma unroll
    for (int g = 0; g < 2; ++g) {
        lsum[g] += __shfl_xor(lsum[g], 16);
        lsum[g] += __shfl_xor(lsum[g], 32);   // lane(m,*) holds full l for qrow m
        #pragma unroll
        for (int r = 0; r < 4; ++r) {
            const float l = __shfl(lsum[g], quad * 4 + r);
            const float val = og[g][r] / l;
            const int row = q0 + wave * 32 + g * 16 + quad * 4 + r;
            const size_t off = ((size_t)row * T_STEPS + t) * 64 + hd * 16 + m;
            unsigned short hh = bf16_rne(val);
            obh[off] = hh;
            obl[off] = bf16_rne(val - bf16_tof(hh));
        }
    }
}

// ---------------------------------------------------------------------------
// Kernel 3: MFMA output projection. out = ob @ Wo^T + bo, hi/lo split both
// operands (3-term product; dropped lo*lo ~ 2^-16 rel).
// ---------------------------------------------------------------------------
__global__ __launch_bounds__(256) void outproj_mfma_kernel(
    const unsigned short* __restrict__ obh, const unsigned short* __restrict__ obl,
    const float* __restrict__ Wo, const float* __restrict__ bo,
    float* __restrict__ out)
{
    __shared__ unsigned short woh[64 * WOS], wol[64 * WOS];
    __shared__ unsigned short oth[64 * OBS2], otl[64 * OBS2];
    __shared__ float sb[64];
    const int tid = threadIdx.x;

    #pragma unroll
    for (int i = 0; i < 16; ++i) {       // stage + split Wo
        int idx = tid + 256 * i;
        int r = idx >> 6, c = idx & 63;
        float w = Wo[idx];
        unsigned short hh = bf16_rne(w);
        woh[r * WOS + c] = hh;
        wol[r * WOS + c] = bf16_rne(w - bf16_tof(hh));
    }
    if (tid < 64) sb[tid] = bo[tid];

    const size_t p0 = (size_t)blockIdx.x * 64;
    #pragma unroll
    for (int i = 0; i < 2; ++i) {        // stage ob tile (bf16 planes)
        int idx = tid + 256 * i;
        int r = idx >> 3, c = (idx & 7) * 8;
        *(uint4*)&oth[r * OBS2 + c] = *(const uint4*)(obh + (p0 + r) * 64 + c);
        *(uint4*)&otl[r * OBS2 + c] = *(const uint4*)(obl + (p0 + r) * 64 + c);
    }
    __syncthreads();

    const int wave = tid >> 6, lane = tid & 63;
    const int m = lane & 15, quad = lane >> 4;
    const int r0 = wave * 16;

    bf16x8 ah[2], al[2];
    #pragma unroll
    for (int kh = 0; kh < 2; ++kh) {
        ah[kh] = *(const bf16x8*)&oth[(r0 + m) * OBS2 + kh * 32 + quad * 8];
        al[kh] = *(const bf16x8*)&otl[(r0 + m) * OBS2 + kh * 32 + quad * 8];
    }

    f32x4 acc[4] = {{0,0,0,0},{0,0,0,0},{0,0,0,0},{0,0,0,0}};
    #pragma unroll
    for (int jt = 0; jt < 4; ++jt) {
        #pragma unroll
        for (int kh = 0; kh < 2; ++kh) {
            bf16x8 bh = *(const bf16x8*)&woh[(jt * 16 + m) * WOS + kh * 32 + quad * 8];
            bf16x8 bl = *(const bf16x8*)&wol[(jt * 16 + m) * WOS + kh * 32 + quad * 8];
            acc[jt] = MFMA_BF16(ah[kh], bh, acc[jt], 0, 0, 0);
            acc[jt] = MFMA_BF16(al[kh], bh, acc[jt], 0, 0, 0);
            acc[jt] = MFMA_BF16(ah[kh], bl, acc[jt], 0, 0, 0);
        }
    }

    #pragma unroll
    for (int jt = 0; jt < 4; ++jt) {
        const float b = sb[jt * 16 + m];
        #pragma unroll
        for (int r = 0; r < 4; ++r)
            out[(p0 + r0 + quad * 4 + r) * 64 + jt * 16 + m] = acc[jt][r] + b;
    }
}

// ---------------------------------------------------------------------------
extern "C" void kernel_launch(void* const* d_in, const int* in_sizes, int n_in,
                              void* d_out, int out_size, void* d_ws, size_t ws_size,
                              hipStream_t stream)
{
    (void)in_sizes; (void)n_in; (void)out_size; (void)ws_size;
    const float* values = (const float*)d_in[0];
    const float* keys   = (const float*)d_in[1];
    const float* query  = (const float*)d_in[2];
    const float* Wv     = (const float*)d_in[3];
    const float* Wk     = (const float*)d_in[4];
    const float* Wq     = (const float*)d_in[5];
    const float* Wo     = (const float*)d_in[6];
    const float* bo     = (const float*)d_in[7];

    const size_t TOT = (size_t)144 * N_NODES * 16;   // 2,359,296 bf16 per plane
    unsigned short* ws16 = (unsigned short*)d_ws;
    unsigned short* qhi  = ws16;
    unsigned short* qlo  = ws16 + 1*TOT;
    unsigned short* khi  = ws16 + 2*TOT;
    unsigned short* klo  = ws16 + 3*TOT;
    unsigned short* vthi = ws16 + 4*TOT;
    unsigned short* vtlo = ws16 + 5*TOT;
    unsigned short* obh  = ws16 + 6*TOT;
    unsigned short* obl  = ws16 + 7*TOT;             // total ws = 8*TOT*2B = 37.75 MB

    proj4_kernel<<<dim3(8, 36), 128, 0, stream>>>(values, keys, query, Wv, Wk, Wq,
                                                  qhi, qlo, khi, klo, vthi, vtlo);
    attn_mfma3_kernel<<<dim3(8 * 144), 256, 0, stream>>>(qhi, qlo, khi, klo, vthi, vtlo,
                                                         obh, obl);
    outproj_mfma_kernel<<<dim3(576), 256, 0, stream>>>(obh, obl, Wo, bo, (float*)d_out);
}

// Round 5
// 145.884 us; speedup vs baseline: 2.0865x; 1.0712x over previous
//
#include <hip/hip_runtime.h>
#include <math.h>

#define N_NODES 1024
#define T_STEPS 36
#define KTILE   128          // k-nodes per attn LDS tile
#define KSTR2   24           // K LDS row stride (bf16): 16 data + 8 pad
#define VTSTR   136          // V^T LDS row stride (bf16): 128 data + 8 pad
#define WOS     72           // outproj Wo LDS stride (bf16)
#define OBS2    72           // outproj ob-tile LDS stride (bf16)
#define YSTR    67           // proj5 LDS row stride (uint32): odd -> v-phase reads <=4-way banks

typedef __bf16  bf16x8 __attribute__((ext_vector_type(8)));
typedef float   f32x4  __attribute__((ext_vector_type(4)));

#define MFMA_BF16 __builtin_amdgcn_mfma_f32_16x16x32_bf16
#define PERM_HI 0x07060302u   // (a,b) -> hi16(b) | hi16(a)<<16
#define PERM_LO 0x05040100u   // (a,b) -> lo16(b) | lo16(a)<<16

__device__ __forceinline__ unsigned short bf16_rne(float f) {
    unsigned int u = __float_as_uint(f);
    u += 0x7FFFu + ((u >> 16) & 1u);
    return (unsigned short)(u >> 16);
}
__device__ __forceinline__ float bf16_tof(unsigned short h) {
    return __uint_as_float(((unsigned int)h) << 16);
}
// RNE-biased uint of fp32 (upper 16 bits = rounded bf16)
__device__ __forceinline__ unsigned int bf16_bias(float f) {
    unsigned int u = __float_as_uint(f);
    return u + 0x7FFFu + ((u >> 16) & 1u);
}
// fp32 -> (hi bf16 << 16) | lo bf16, hi/lo split
__device__ __forceinline__ unsigned int split_pack(float a) {
    unsigned short hi = bf16_rne(a);
    unsigned short lo = bf16_rne(a - bf16_tof(hi));
    return ((unsigned int)hi << 16) | lo;
}

// ---------------------------------------------------------------------------
// Kernel 1 (proj5): read-coalesced -> LDS -> write-coalesced projection.
// Block = 128 thr = tile (64 n) x (2 t), one matrix (blockIdx.y: 0=v,1=k,2=q).
// Phase A: thread = one (n,t) row, lanes cover consecutive rows -> coalesced
//          reads; compute 4hd x 16e dots (bitwise-identical fmaf chains);
//          stage packed hi|lo uints in LDS.
// Phase B: remap lanes to output order; v_perm splits hi/lo planes.
//   q/k out: [t][h][n][16]  (2KB contiguous per (t,hd,plane) chunk)
//   v out:   [t][h][d][n]   (128B contiguous per (t,hd,e) octet-group)
// ---------------------------------------------------------------------------
__global__ __launch_bounds__(128) void proj5_kernel(
    const float* __restrict__ vin, const float* __restrict__ kin, const float* __restrict__ qin,
    const float* __restrict__ Wv, const float* __restrict__ Wk, const float* __restrict__ Wq,
    unsigned short* __restrict__ qhi, unsigned short* __restrict__ qlo,
    unsigned short* __restrict__ khi, unsigned short* __restrict__ klo,
    unsigned short* __restrict__ vthi, unsigned short* __restrict__ vtlo)
{
    __shared__ float sW[256];
    __shared__ unsigned int ys[128 * YSTR];   // [row(nl*2+tl)][hd*16+e] packed hi|lo

    const int tid = threadIdx.x;
    const int mat = blockIdx.y;               // 0=v, 1=k, 2=q
    const int nt  = blockIdx.x & 15;
    const int tt  = blockIdx.x >> 4;          // 0..17
    const int n0  = nt * 64, t0 = tt * 2;

    const float* in = (mat == 0) ? vin : (mat == 1) ? kin : qin;
    const float* W  = (mat == 0) ? Wv  : (mat == 1) ? Wk  : Wq;
    sW[tid] = W[tid]; sW[tid + 128] = W[tid + 128];
    __syncthreads();

    // ---- Phase A: coalesced read + project + stage ----
    {
        const int nl = tid >> 1, tl = tid & 1;
        const size_t p = ((size_t)(n0 + nl)) * T_STEPS + (t0 + tl);
        const float4* src = (const float4*)(in + p * 64);
        float x[64];
        #pragma unroll
        for (int i = 0; i < 16; ++i) {
            float4 f = src[i];
            x[4*i] = f.x; x[4*i+1] = f.y; x[4*i+2] = f.z; x[4*i+3] = f.w;
        }
        const float scale = (mat == 2) ? 0.18033688011112042f : 1.0f;  // log2(e)/8 on Q
        unsigned int* yrow = &ys[tid * YSTR];
        #pragma unroll
        for (int e = 0; e < 16; ++e) {
            float4 w0 = *(const float4*)&sW[e*16+0],  w1 = *(const float4*)&sW[e*16+4];
            float4 w2 = *(const float4*)&sW[e*16+8],  w3 = *(const float4*)&sW[e*16+12];
            #pragma unroll
            for (int hd = 0; hd < 4; ++hd) {
                const float* xr = &x[hd*16];
                float a = xr[0]*w0.x;
                a = fmaf(xr[1],w0.y,a);  a = fmaf(xr[2],w0.z,a);  a = fmaf(xr[3],w0.w,a);
                a = fmaf(xr[4],w1.x,a);  a = fmaf(xr[5],w1.y,a);  a = fmaf(xr[6],w1.z,a);  a = fmaf(xr[7],w1.w,a);
                a = fmaf(xr[8],w2.x,a);  a = fmaf(xr[9],w2.y,a);  a = fmaf(xr[10],w2.z,a); a = fmaf(xr[11],w2.w,a);
                a = fmaf(xr[12],w3.x,a); a = fmaf(xr[13],w3.y,a); a = fmaf(xr[14],w3.z,a); a = fmaf(xr[15],w3.w,a);
                yrow[hd*16 + e] = split_pack(a * scale);
            }
        }
    }
    __syncthreads();

    // ---- Phase B: coalesced writes ----
    if (mat != 0) {
        unsigned short* ohi = (mat == 1) ? khi : qhi;
        unsigned short* olo = (mat == 1) ? klo : qlo;
        const int nl2 = tid >> 1, eh = tid & 1;
        #pragma unroll
        for (int pass = 0; pass < 8; ++pass) {
            const int tl2 = pass & 1, hd = pass >> 1;
            const unsigned int* yr = &ys[(nl2*2 + tl2) * YSTR + hd*16 + eh*8];
            unsigned int u0 = yr[0], u1 = yr[1], u2 = yr[2], u3 = yr[3];
            unsigned int u4 = yr[4], u5 = yr[5], u6 = yr[6], u7 = yr[7];
            uint4 hi4, lo4;
            hi4.x = __builtin_amdgcn_perm(u1, u0, PERM_HI);
            hi4.y = __builtin_amdgcn_perm(u3, u2, PERM_HI);
            hi4.z = __builtin_amdgcn_perm(u5, u4, PERM_HI);
            hi4.w = __builtin_amdgcn_perm(u7, u6, PERM_HI);
            lo4.x = __builtin_amdgcn_perm(u1, u0, PERM_LO);
            lo4.y = __builtin_amdgcn_perm(u3, u2, PERM_LO);
            lo4.z = __builtin_amdgcn_perm(u5, u4, PERM_LO);
            lo4.w = __builtin_amdgcn_perm(u7, u6, PERM_LO);
            const int th = (t0 + tl2) * 4 + hd;
            const size_t off = ((size_t)th * N_NODES + n0 + nl2) * 16 + eh * 8;
            *(uint4*)(ohi + off) = hi4;
            *(uint4*)(olo + off) = lo4;
        }
    } else {
        const int e = tid >> 3, ng = tid & 7;
        #pragma unroll
        for (int pass = 0; pass < 8; ++pass) {
            const int tl2 = pass & 1, hd = pass >> 1;
            unsigned int u[8];
            #pragma unroll
            for (int j = 0; j < 8; ++j)
                u[j] = ys[((ng*8 + j)*2 + tl2) * YSTR + hd*16 + e];
            uint4 hi4, lo4;
            hi4.x = __builtin_amdgcn_perm(u[1], u[0], PERM_HI);
            hi4.y = __builtin_amdgcn_perm(u[3], u[2], PERM_HI);
            hi4.z = __builtin_amdgcn_perm(u[5], u[4], PERM_HI);
            hi4.w = __builtin_amdgcn_perm(u[7], u[6], PERM_HI);
            lo4.x = __builtin_amdgcn_perm(u[1], u[0], PERM_LO);
            lo4.y = __builtin_amdgcn_perm(u[3], u[2], PERM_LO);
            lo4.z = __builtin_amdgcn_perm(u[5], u[4], PERM_LO);
            lo4.w = __builtin_amdgcn_perm(u[7], u[6], PERM_LO);
            const int th = (t0 + tl2) * 4 + hd;
            const size_t off = ((size_t)th * 16 + e) * N_NODES + n0 + ng * 8;
            *(uint4*)(vthi + off) = hi4;
            *(uint4*)(vtlo + off) = lo4;
        }
    }
}

// ---------------------------------------------------------------------------
// Kernel 2: MFMA flash attention — P never touches LDS (unchanged from R4).
// ---------------------------------------------------------------------------
__global__ __launch_bounds__(256, 4) void attn_mfma3_kernel(
    const unsigned short* __restrict__ qhi, const unsigned short* __restrict__ qlo,
    const unsigned short* __restrict__ khi, const unsigned short* __restrict__ klo,
    const unsigned short* __restrict__ vthi, const unsigned short* __restrict__ vtlo,
    unsigned short* __restrict__ obh, unsigned short* __restrict__ obl)
{
    __shared__ unsigned short khi_s[KTILE * KSTR2];
    __shared__ unsigned short klo_s[KTILE * KSTR2];
    __shared__ unsigned short vthi_s[16 * VTSTR];   // permuted node order per 32-chunk
    __shared__ unsigned short vtlo_s[16 * VTSTR];

    const int tid  = threadIdx.x;
    const int wave = tid >> 6, lane = tid & 63;
    const int m = lane & 15, quad = lane >> 4;

    const int bid = blockIdx.x;
    const int th  = bid % 144;
    const int qb  = bid / 144;
    const int t   = th >> 2, hd = th & 3;
    const int q0  = qb * 128;
    const size_t base_th = (size_t)th * N_NODES;

    const bf16x8 bzero = {};
    bf16x8 b1q[2], b2q[2];
    #pragma unroll
    for (int g = 0; g < 2; ++g) {
        const int qrow = q0 + wave * 32 + g * 16 + m;
        b1q[g] = *(const bf16x8*)(qhi + (base_th + qrow) * 16 + (quad & 1) * 8);
        b2q[g] = (quad < 2)
            ? *(const bf16x8*)(qlo + (base_th + qrow) * 16 + (quad & 1) * 8) : bzero;
    }

    f32x4 og[2] = {{0.f,0.f,0.f,0.f},{0.f,0.f,0.f,0.f}};
    float lsum[2] = {0.f, 0.f};
    const unsigned short* kbase = (quad < 2) ? khi_s : klo_s;
    const int koff = m * KSTR2 + (quad & 1) * 8;
    const int voff = m * VTSTR + quad * 8;

    for (int kt = 0; kt < N_NODES; kt += KTILE) {
        __syncthreads();
        if (tid < 128) {
            const int r = tid;
            const uint4* gh = (const uint4*)(khi + (base_th + kt + r) * 16);
            const uint4* gl = (const uint4*)(klo + (base_th + kt + r) * 16);
            uint4 a0 = gh[0], a1 = gh[1], c0 = gl[0], c1 = gl[1];
            *(uint4*)&khi_s[r * KSTR2]     = a0;
            *(uint4*)&khi_s[r * KSTR2 + 8] = a1;
            *(uint4*)&klo_s[r * KSTR2]     = c0;
            *(uint4*)&klo_s[r * KSTR2 + 8] = c1;
        } else {
            const int j = tid - 128;
            const int sel = j >> 6, d = (j >> 2) & 15, part = j & 3;
            const unsigned short* src = (sel ? vtlo : vthi)
                + ((size_t)th * 16 + d) * N_NODES + kt + part * 32;
            unsigned short* dst = (sel ? vtlo_s : vthi_s) + d * VTSTR + part * 32;
            uint4 a0 = ((const uint4*)src)[0], a1 = ((const uint4*)src)[1];
            uint4 a2 = ((const uint4*)src)[2], a3 = ((const uint4*)src)[3];
            // node n (0..31) -> pos ((n>>2)&3)*8 + (n>>4)*4 + (n&3)
            *(uint2*)&dst[0]  = make_uint2(a0.x, a0.y);
            *(uint2*)&dst[8]  = make_uint2(a0.z, a0.w);
            *(uint2*)&dst[16] = make_uint2(a1.x, a1.y);
            *(uint2*)&dst[24] = make_uint2(a1.z, a1.w);
            *(uint2*)&dst[4]  = make_uint2(a2.x, a2.y);
            *(uint2*)&dst[12] = make_uint2(a2.z, a2.w);
            *(uint2*)&dst[20] = make_uint2(a3.x, a3.y);
            *(uint2*)&dst[28] = make_uint2(a3.z, a3.w);
        }
        __syncthreads();

        #pragma unroll
        for (int c = 0; c < 4; ++c) {
            bf16x8 a0 = *(const bf16x8*)(kbase + (2*c    ) * 16 * KSTR2 + koff);
            bf16x8 a1 = *(const bf16x8*)(kbase + (2*c + 1) * 16 * KSTR2 + koff);
            unsigned int pk[2][4];
            #pragma unroll
            for (int g = 0; g < 2; ++g) {
                f32x4 s0 = MFMA_BF16(a0, b1q[g], (f32x4){0.f,0.f,0.f,0.f}, 0, 0, 0);
                s0 = MFMA_BF16(a0, b2q[g], s0, 0, 0, 0);
                f32x4 s1 = MFMA_BF16(a1, b1q[g], (f32x4){0.f,0.f,0.f,0.f}, 0, 0, 0);
                s1 = MFMA_BF16(a1, b2q[g], s1, 0, 0, 0);
                unsigned int u[8];
                float ls = 0.f;
                #pragma unroll
                for (int r = 0; r < 4; ++r) {
                    u[r]   = bf16_bias(__builtin_amdgcn_exp2f(s0[r]));
                    u[4+r] = bf16_bias(__builtin_amdgcn_exp2f(s1[r]));
                    ls += __uint_as_float(u[r]   & 0xFFFF0000u);
                    ls += __uint_as_float(u[4+r] & 0xFFFF0000u);
                }
                lsum[g] += ls;
                pk[g][0] = __builtin_amdgcn_perm(u[1], u[0], PERM_HI);
                pk[g][1] = __builtin_amdgcn_perm(u[3], u[2], PERM_HI);
                pk[g][2] = __builtin_amdgcn_perm(u[5], u[4], PERM_HI);
                pk[g][3] = __builtin_amdgcn_perm(u[7], u[6], PERM_HI);
            }
            bf16x8 vh = *(const bf16x8*)&vthi_s[voff + c * 32];
            bf16x8 vl = *(const bf16x8*)&vtlo_s[voff + c * 32];
            #pragma unroll
            for (int g = 0; g < 2; ++g) {
                union { unsigned int u[4]; bf16x8 v; } ap;
                ap.u[0] = pk[g][0]; ap.u[1] = pk[g][1];
                ap.u[2] = pk[g][2]; ap.u[3] = pk[g][3];
                og[g] = MFMA_BF16(ap.v, vh, og[g], 0, 0, 0);
                og[g] = MFMA_BF16(ap.v, vl, og[g], 0, 0, 0);
            }
        }
    }

    #pragma unroll
    for (int g = 0; g < 2; ++g) {
        lsum[g] += __shfl_xor(lsum[g], 16);
        lsum[g] += __shfl_xor(lsum[g], 32);
        #pragma unroll
        for (int r = 0; r < 4; ++r) {
            const float l = __shfl(lsum[g], quad * 4 + r);
            const float val = og[g][r] / l;
            const int row = q0 + wave * 32 + g * 16 + quad * 4 + r;
            const size_t off = ((size_t)row * T_STEPS + t) * 64 + hd * 16 + m;
            unsigned short hh = bf16_rne(val);
            obh[off] = hh;
            obl[off] = bf16_rne(val - bf16_tof(hh));
        }
    }
}

// ---------------------------------------------------------------------------
// Kernel 3: MFMA output projection (unchanged from R4).
// ---------------------------------------------------------------------------
__global__ __launch_bounds__(256) void outproj_mfma_kernel(
    const unsigned short* __restrict__ obh, const unsigned short* __restrict__ obl,
    const float* __restrict__ Wo, const float* __restrict__ bo,
    float* __restrict__ out)
{
    __shared__ unsigned short woh[64 * WOS], wol[64 * WOS];
    __shared__ unsigned short oth[64 * OBS2], otl[64 * OBS2];
    __shared__ float sb[64];
    const int tid = threadIdx.x;

    #pragma unroll
    for (int i = 0; i < 16; ++i) {
        int idx = tid + 256 * i;
        int r = idx >> 6, c = idx & 63;
        float w = Wo[idx];
        unsigned short hh = bf16_rne(w);
        woh[r * WOS + c] = hh;
        wol[r * WOS + c] = bf16_rne(w - bf16_tof(hh));
    }
    if (tid < 64) sb[tid] = bo[tid];

    const size_t p0 = (size_t)blockIdx.x * 64;
    #pragma unroll
    for (int i = 0; i < 2; ++i) {
        int idx = tid + 256 * i;
        int r = idx >> 3, c = (idx & 7) * 8;
        *(uint4*)&oth[r * OBS2 + c] = *(const uint4*)(obh + (p0 + r) * 64 + c);
        *(uint4*)&otl[r * OBS2 + c] = *(const uint4*)(obl + (p0 + r) * 64 + c);
    }
    __syncthreads();

    const int wave = tid >> 6, lane = tid & 63;
    const int m = lane & 15, quad = lane >> 4;
    const int r0 = wave * 16;

    bf16x8 ah[2], al[2];
    #pragma unroll
    for (int kh = 0; kh < 2; ++kh) {
        ah[kh] = *(const bf16x8*)&oth[(r0 + m) * OBS2 + kh * 32 + quad * 8];
        al[kh] = *(const bf16x8*)&otl[(r0 + m) * OBS2 + kh * 32 + quad * 8];
    }

    f32x4 acc[4] = {{0,0,0,0},{0,0,0,0},{0,0,0,0},{0,0,0,0}};
    #pragma unroll
    for (int jt = 0; jt < 4; ++jt) {
        #pragma unroll
        for (int kh = 0; kh < 2; ++kh) {
            bf16x8 bh = *(const bf16x8*)&woh[(jt * 16 + m) * WOS + kh * 32 + quad * 8];
            bf16x8 bl = *(const bf16x8*)&wol[(jt * 16 + m) * WOS + kh * 32 + quad * 8];
            acc[jt] = MFMA_BF16(ah[kh], bh, acc[jt], 0, 0, 0);
            acc[jt] = MFMA_BF16(al[kh], bh, acc[jt], 0, 0, 0);
            acc[jt] = MFMA_BF16(ah[kh], bl, acc[jt], 0, 0, 0);
        }
    }

    #pragma unroll
    for (int jt = 0; jt < 4; ++jt) {
        const float b = sb[jt * 16 + m];
        #pragma unroll
        for (int r = 0; r < 4; ++r)
            out[(p0 + r0 + quad * 4 + r) * 64 + jt * 16 + m] = acc[jt][r] + b;
    }
}

// ---------------------------------------------------------------------------
extern "C" void kernel_launch(void* const* d_in, const int* in_sizes, int n_in,
                              void* d_out, int out_size, void* d_ws, size_t ws_size,
                              hipStream_t stream)
{
    (void)in_sizes; (void)n_in; (void)out_size; (void)ws_size;
    const float* values = (const float*)d_in[0];
    const float* keys   = (const float*)d_in[1];
    const float* query  = (const float*)d_in[2];
    const float* Wv     = (const float*)d_in[3];
    const float* Wk     = (const float*)d_in[4];
    const float* Wq     = (const float*)d_in[5];
    const float* Wo     = (const float*)d_in[6];
    const float* bo     = (const float*)d_in[7];

    const size_t TOT = (size_t)144 * N_NODES * 16;   // 2,359,296 bf16 per plane
    unsigned short* ws16 = (unsigned short*)d_ws;
    unsigned short* qhi  = ws16;
    unsigned short* qlo  = ws16 + 1*TOT;
    unsigned short* khi  = ws16 + 2*TOT;
    unsigned short* klo  = ws16 + 3*TOT;
    unsigned short* vthi = ws16 + 4*TOT;
    unsigned short* vtlo = ws16 + 5*TOT;
    unsigned short* obh  = ws16 + 6*TOT;
    unsigned short* obl  = ws16 + 7*TOT;             // total ws = 8*TOT*2B = 37.75 MB

    // 288 = 16 n-tiles x 18 t-tiles; y = matrix (0=v,1=k,2=q)
    proj5_kernel<<<dim3(288, 3), 128, 0, stream>>>(values, keys, query, Wv, Wk, Wq,
                                                   qhi, qlo, khi, klo, vthi, vtlo);
    attn_mfma3_kernel<<<dim3(8 * 144), 256, 0, stream>>>(qhi, qlo, khi, klo, vthi, vtlo,
                                                         obh, obl);
    outproj_mfma_kernel<<<dim3(576), 256, 0, stream>>>(obh, obl, Wo, bo, (float*)d_out);
}

// Round 6
// 137.960 us; speedup vs baseline: 2.2063x; 1.0574x over previous
//
#include <hip/hip_runtime.h>
#include <math.h>

#define N_NODES 1024
#define T_STEPS 36
#define KTILE   128          // k-nodes per attn LDS tile
#define KSTR2   24           // K LDS row stride (bf16): 16 data + 8 pad
#define VTSTR   136          // V^T LDS row stride (bf16): 128 data + 8 pad
#define WOS     72           // outproj Wo LDS stride (bf16)
#define OBS2    72           // outproj ob-tile LDS stride (bf16)
#define YSTR    67           // proj5 LDS row stride (uint32)

typedef __bf16  bf16x8 __attribute__((ext_vector_type(8)));
typedef float   f32x4  __attribute__((ext_vector_type(4)));

#define MFMA_BF16 __builtin_amdgcn_mfma_f32_16x16x32_bf16
#define PERM_HI 0x07060302u   // (a,b) -> hi16(b) | hi16(a)<<16
#define PERM_LO 0x05040100u   // (a,b) -> lo16(b) | lo16(a)<<16

__device__ __forceinline__ unsigned short bf16_rne(float f) {
    unsigned int u = __float_as_uint(f);
    u += 0x7FFFu + ((u >> 16) & 1u);
    return (unsigned short)(u >> 16);
}
__device__ __forceinline__ float bf16_tof(unsigned short h) {
    return __uint_as_float(((unsigned int)h) << 16);
}
// fp32 -> (hi bf16 << 16) | lo bf16, hi/lo split
__device__ __forceinline__ unsigned int split_pack(float a) {
    unsigned short hi = bf16_rne(a);
    unsigned short lo = bf16_rne(a - bf16_tof(hi));
    return ((unsigned int)hi << 16) | lo;
}

// ---------------------------------------------------------------------------
// Kernel 1 (proj5): read-coalesced -> LDS -> write-coalesced projection.
// (unchanged from R5 — it fell off the top-5)
// ---------------------------------------------------------------------------
__global__ __launch_bounds__(128) void proj5_kernel(
    const float* __restrict__ vin, const float* __restrict__ kin, const float* __restrict__ qin,
    const float* __restrict__ Wv, const float* __restrict__ Wk, const float* __restrict__ Wq,
    unsigned short* __restrict__ qhi, unsigned short* __restrict__ qlo,
    unsigned short* __restrict__ khi, unsigned short* __restrict__ klo,
    unsigned short* __restrict__ vthi, unsigned short* __restrict__ vtlo)
{
    __shared__ float sW[256];
    __shared__ unsigned int ys[128 * YSTR];   // [row(nl*2+tl)][hd*16+e] packed hi|lo

    const int tid = threadIdx.x;
    const int mat = blockIdx.y;               // 0=v, 1=k, 2=q
    const int nt  = blockIdx.x & 15;
    const int tt  = blockIdx.x >> 4;          // 0..17
    const int n0  = nt * 64, t0 = tt * 2;

    const float* in = (mat == 0) ? vin : (mat == 1) ? kin : qin;
    const float* W  = (mat == 0) ? Wv  : (mat == 1) ? Wk  : Wq;
    sW[tid] = W[tid]; sW[tid + 128] = W[tid + 128];
    __syncthreads();

    // ---- Phase A: coalesced read + project + stage ----
    {
        const int nl = tid >> 1, tl = tid & 1;
        const size_t p = ((size_t)(n0 + nl)) * T_STEPS + (t0 + tl);
        const float4* src = (const float4*)(in + p * 64);
        float x[64];
        #pragma unroll
        for (int i = 0; i < 16; ++i) {
            float4 f = src[i];
            x[4*i] = f.x; x[4*i+1] = f.y; x[4*i+2] = f.z; x[4*i+3] = f.w;
        }
        const float scale = (mat == 2) ? 0.18033688011112042f : 1.0f;  // log2(e)/8 on Q
        unsigned int* yrow = &ys[tid * YSTR];
        #pragma unroll
        for (int e = 0; e < 16; ++e) {
            float4 w0 = *(const float4*)&sW[e*16+0],  w1 = *(const float4*)&sW[e*16+4];
            float4 w2 = *(const float4*)&sW[e*16+8],  w3 = *(const float4*)&sW[e*16+12];
            #pragma unroll
            for (int hd = 0; hd < 4; ++hd) {
                const float* xr = &x[hd*16];
                float a = xr[0]*w0.x;
                a = fmaf(xr[1],w0.y,a);  a = fmaf(xr[2],w0.z,a);  a = fmaf(xr[3],w0.w,a);
                a = fmaf(xr[4],w1.x,a);  a = fmaf(xr[5],w1.y,a);  a = fmaf(xr[6],w1.z,a);  a = fmaf(xr[7],w1.w,a);
                a = fmaf(xr[8],w2.x,a);  a = fmaf(xr[9],w2.y,a);  a = fmaf(xr[10],w2.z,a); a = fmaf(xr[11],w2.w,a);
                a = fmaf(xr[12],w3.x,a); a = fmaf(xr[13],w3.y,a); a = fmaf(xr[14],w3.z,a); a = fmaf(xr[15],w3.w,a);
                yrow[hd*16 + e] = split_pack(a * scale);
            }
        }
    }
    __syncthreads();

    // ---- Phase B: coalesced writes ----
    if (mat != 0) {
        unsigned short* ohi = (mat == 1) ? khi : qhi;
        unsigned short* olo = (mat == 1) ? klo : qlo;
        const int nl2 = tid >> 1, eh = tid & 1;
        #pragma unroll
        for (int pass = 0; pass < 8; ++pass) {
            const int tl2 = pass & 1, hd = pass >> 1;
            const unsigned int* yr = &ys[(nl2*2 + tl2) * YSTR + hd*16 + eh*8];
            unsigned int u0 = yr[0], u1 = yr[1], u2 = yr[2], u3 = yr[3];
            unsigned int u4 = yr[4], u5 = yr[5], u6 = yr[6], u7 = yr[7];
            uint4 hi4, lo4;
            hi4.x = __builtin_amdgcn_perm(u1, u0, PERM_HI);
            hi4.y = __builtin_amdgcn_perm(u3, u2, PERM_HI);
            hi4.z = __builtin_amdgcn_perm(u5, u4, PERM_HI);
            hi4.w = __builtin_amdgcn_perm(u7, u6, PERM_HI);
            lo4.x = __builtin_amdgcn_perm(u1, u0, PERM_LO);
            lo4.y = __builtin_amdgcn_perm(u3, u2, PERM_LO);
            lo4.z = __builtin_amdgcn_perm(u5, u4, PERM_LO);
            lo4.w = __builtin_amdgcn_perm(u7, u6, PERM_LO);
            const int th = (t0 + tl2) * 4 + hd;
            const size_t off = ((size_t)th * N_NODES + n0 + nl2) * 16 + eh * 8;
            *(uint4*)(ohi + off) = hi4;
            *(uint4*)(olo + off) = lo4;
        }
    } else {
        const int e = tid >> 3, ng = tid & 7;
        #pragma unroll
        for (int pass = 0; pass < 8; ++pass) {
            const int tl2 = pass & 1, hd = pass >> 1;
            unsigned int u[8];
            #pragma unroll
            for (int j = 0; j < 8; ++j)
                u[j] = ys[((ng*8 + j)*2 + tl2) * YSTR + hd*16 + e];
            uint4 hi4, lo4;
            hi4.x = __builtin_amdgcn_perm(u[1], u[0], PERM_HI);
            hi4.y = __builtin_amdgcn_perm(u[3], u[2], PERM_HI);
            hi4.z = __builtin_amdgcn_perm(u[5], u[4], PERM_HI);
            hi4.w = __builtin_amdgcn_perm(u[7], u[6], PERM_HI);
            lo4.x = __builtin_amdgcn_perm(u[1], u[0], PERM_LO);
            lo4.y = __builtin_amdgcn_perm(u[3], u[2], PERM_LO);
            lo4.z = __builtin_amdgcn_perm(u[5], u[4], PERM_LO);
            lo4.w = __builtin_amdgcn_perm(u[7], u[6], PERM_LO);
            const int th = (t0 + tl2) * 4 + hd;
            const size_t off = ((size_t)th * 16 + e) * N_NODES + n0 + ng * 8;
            *(uint4*)(vthi + off) = hi4;
            *(uint4*)(vtlo + off) = lo4;
        }
    }
}

// ---------------------------------------------------------------------------
// Kernel 2 (attn_mfma4): MFMA flash attention, occupancy + VALU-diet rev.
// Block = 128 thr (2 waves), QT=64 q-rows; grid 2304 (= 9 blocks/CU offered,
// LDS 21KB -> 7 resident). Wave owns 32 q-rows (g=2), same ILP as R5.
// lsum via ones-MFMA (l lands in C-layout where epilogue needs it, zero
// shuffles); P packed by native bf16 cvt; fixed-shift softmax.
// ---------------------------------------------------------------------------
__global__ __launch_bounds__(128, 4) void attn_mfma4_kernel(
    const unsigned short* __restrict__ qhi, const unsigned short* __restrict__ qlo,
    const unsigned short* __restrict__ khi, const unsigned short* __restrict__ klo,
    const unsigned short* __restrict__ vthi, const unsigned short* __restrict__ vtlo,
    unsigned short* __restrict__ obh, unsigned short* __restrict__ obl)
{
    __shared__ unsigned short khi_s[KTILE * KSTR2];
    __shared__ unsigned short klo_s[KTILE * KSTR2];
    __shared__ unsigned short vthi_s[16 * VTSTR];   // permuted node order per 32-chunk
    __shared__ unsigned short vtlo_s[16 * VTSTR];

    const int tid  = threadIdx.x;
    const int wave = tid >> 6, lane = tid & 63;
    const int m = lane & 15, quad = lane >> 4;

    const int bid = blockIdx.x;
    const int th  = bid % 144;          // th mod 8 stable -> XCD-local K/V reuse
    const int qb  = bid / 144;
    const int t   = th >> 2, hd = th & 3;
    const int q0  = qb * 64;
    const size_t base_th = (size_t)th * N_NODES;

    // Q as B-operand, 2 rowgroups resident in registers.
    const bf16x8 bzero = {};
    bf16x8 b1q[2], b2q[2];
    #pragma unroll
    for (int g = 0; g < 2; ++g) {
        const int qrow = q0 + wave * 32 + g * 16 + m;
        b1q[g] = *(const bf16x8*)(qhi + (base_th + qrow) * 16 + (quad & 1) * 8);
        b2q[g] = (quad < 2)
            ? *(const bf16x8*)(qlo + (base_th + qrow) * 16 + (quad & 1) * 8) : bzero;
    }

    // all-ones B fragment for the l row-sum MFMA
    union { unsigned short su[8]; bf16x8 v; } onesu;
    #pragma unroll
    for (int i = 0; i < 8; ++i) onesu.su[i] = 0x3F80;
    const bf16x8 bones = onesu.v;

    f32x4 og[2]   = {{0.f,0.f,0.f,0.f},{0.f,0.f,0.f,0.f}};
    f32x4 lacc[2] = {{0.f,0.f,0.f,0.f},{0.f,0.f,0.f,0.f}};
    const unsigned short* kbase = (quad < 2) ? khi_s : klo_s;
    const int koff = m * KSTR2 + (quad & 1) * 8;
    const int voff = m * VTSTR + quad * 8;

    // staging assignments (every thread: one K row + one V quarter-row)
    const int vsel = tid >> 6, vd = (tid >> 2) & 15, vpart = tid & 3;
    const unsigned short* vsrc0 = (vsel ? vtlo : vthi)
        + ((size_t)th * 16 + vd) * N_NODES + vpart * 32;
    unsigned short* vdst = (vsel ? vtlo_s : vthi_s) + vd * VTSTR + vpart * 32;

    for (int kt = 0; kt < N_NODES; kt += KTILE) {
        __syncthreads();
        {   // K rows hi+lo
            const uint4* gh = (const uint4*)(khi + (base_th + kt + tid) * 16);
            const uint4* gl = (const uint4*)(klo + (base_th + kt + tid) * 16);
            uint4 a0 = gh[0], a1 = gh[1], c0 = gl[0], c1 = gl[1];
            *(uint4*)&khi_s[tid * KSTR2]     = a0;
            *(uint4*)&khi_s[tid * KSTR2 + 8] = a1;
            *(uint4*)&klo_s[tid * KSTR2]     = c0;
            *(uint4*)&klo_s[tid * KSTR2 + 8] = c1;
        }
        {   // V^T quarter-row, permuted node order
            const unsigned short* src = vsrc0 + kt;
            uint4 a0 = ((const uint4*)src)[0], a1 = ((const uint4*)src)[1];
            uint4 a2 = ((const uint4*)src)[2], a3 = ((const uint4*)src)[3];
            // node n (0..31) -> pos ((n>>2)&3)*8 + (n>>4)*4 + (n&3)
            *(uint2*)&vdst[0]  = make_uint2(a0.x, a0.y);
            *(uint2*)&vdst[8]  = make_uint2(a0.z, a0.w);
            *(uint2*)&vdst[16] = make_uint2(a1.x, a1.y);
            *(uint2*)&vdst[24] = make_uint2(a1.z, a1.w);
            *(uint2*)&vdst[4]  = make_uint2(a2.x, a2.y);
            *(uint2*)&vdst[12] = make_uint2(a2.z, a2.w);
            *(uint2*)&vdst[20] = make_uint2(a3.x, a3.y);
            *(uint2*)&vdst[28] = make_uint2(a3.z, a3.w);
        }
        __syncthreads();

        #pragma unroll
        for (int c = 0; c < 4; ++c) {    // 32-node group = S-tiles 2c, 2c+1
            bf16x8 a0 = *(const bf16x8*)(kbase + (2*c    ) * 16 * KSTR2 + koff);
            bf16x8 a1 = *(const bf16x8*)(kbase + (2*c + 1) * 16 * KSTR2 + koff);
            bf16x8 vh = *(const bf16x8*)&vthi_s[voff + c * 32];
            bf16x8 vl = *(const bf16x8*)&vtlo_s[voff + c * 32];
            #pragma unroll
            for (int g = 0; g < 2; ++g) {
                f32x4 s0 = MFMA_BF16(a0, b1q[g], (f32x4){0.f,0.f,0.f,0.f}, 0, 0, 0);
                s0 = MFMA_BF16(a0, b2q[g], s0, 0, 0, 0);
                f32x4 s1 = MFMA_BF16(a1, b1q[g], (f32x4){0.f,0.f,0.f,0.f}, 0, 0, 0);
                s1 = MFMA_BF16(a1, b2q[g], s1, 0, 0, 0);
                union { __bf16 b[8]; bf16x8 v; } ap;
                ap.b[0] = (__bf16)__builtin_amdgcn_exp2f(s0[0]);
                ap.b[1] = (__bf16)__builtin_amdgcn_exp2f(s0[1]);
                ap.b[2] = (__bf16)__builtin_amdgcn_exp2f(s0[2]);
                ap.b[3] = (__bf16)__builtin_amdgcn_exp2f(s0[3]);
                ap.b[4] = (__bf16)__builtin_amdgcn_exp2f(s1[0]);
                ap.b[5] = (__bf16)__builtin_amdgcn_exp2f(s1[1]);
                ap.b[6] = (__bf16)__builtin_amdgcn_exp2f(s1[2]);
                ap.b[7] = (__bf16)__builtin_amdgcn_exp2f(s1[3]);
                lacc[g] = MFMA_BF16(ap.v, bones, lacc[g], 0, 0, 0);  // l += row-sum(P)
                og[g]   = MFMA_BF16(ap.v, vh, og[g], 0, 0, 0);
                og[g]   = MFMA_BF16(ap.v, vl, og[g], 0, 0, 0);
            }
        }
    }

    // ---- epilogue: l is already in C-layout (same row mapping as og) ----
    #pragma unroll
    for (int g = 0; g < 2; ++g) {
        #pragma unroll
        for (int r = 0; r < 4; ++r) {
            const float val = og[g][r] * __builtin_amdgcn_rcpf(lacc[g][r]);
            const int row = q0 + wave * 32 + g * 16 + quad * 4 + r;
            const size_t off = ((size_t)row * T_STEPS + t) * 64 + hd * 16 + m;
            unsigned short hh = bf16_rne(val);
            obh[off] = hh;
            obl[off] = bf16_rne(val - bf16_tof(hh));
        }
    }
}

// ---------------------------------------------------------------------------
// Kernel 3: MFMA output projection (unchanged from R4/R5).
// ---------------------------------------------------------------------------
__global__ __launch_bounds__(256) void outproj_mfma_kernel(
    const unsigned short* __restrict__ obh, const unsigned short* __restrict__ obl,
    const float* __restrict__ Wo, const float* __restrict__ bo,
    float* __restrict__ out)
{
    __shared__ unsigned short woh[64 * WOS], wol[64 * WOS];
    __shared__ unsigned short oth[64 * OBS2], otl[64 * OBS2];
    __shared__ float sb[64];
    const int tid = threadIdx.x;

    #pragma unroll
    for (int i = 0; i < 16; ++i) {
        int idx = tid + 256 * i;
        int r = idx >> 6, c = idx & 63;
        float w = Wo[idx];
        unsigned short hh = bf16_rne(w);
        woh[r * WOS + c] = hh;
        wol[r * WOS + c] = bf16_rne(w - bf16_tof(hh));
    }
    if (tid < 64) sb[tid] = bo[tid];

    const size_t p0 = (size_t)blockIdx.x * 64;
    #pragma unroll
    for (int i = 0; i < 2; ++i) {
        int idx = tid + 256 * i;
        int r = idx >> 3, c = (idx & 7) * 8;
        *(uint4*)&oth[r * OBS2 + c] = *(const uint4*)(obh + (p0 + r) * 64 + c);
        *(uint4*)&otl[r * OBS2 + c] = *(const uint4*)(obl + (p0 + r) * 64 + c);
    }
    __syncthreads();

    const int wave = tid >> 6, lane = tid & 63;
    const int m = lane & 15, quad = lane >> 4;
    const int r0 = wave * 16;

    bf16x8 ah[2], al[2];
    #pragma unroll
    for (int kh = 0; kh < 2; ++kh) {
        ah[kh] = *(const bf16x8*)&oth[(r0 + m) * OBS2 + kh * 32 + quad * 8];
        al[kh] = *(const bf16x8*)&otl[(r0 + m) * OBS2 + kh * 32 + quad * 8];
    }

    f32x4 acc[4] = {{0,0,0,0},{0,0,0,0},{0,0,0,0},{0,0,0,0}};
    #pragma unroll
    for (int jt = 0; jt < 4; ++jt) {
        #pragma unroll
        for (int kh = 0; kh < 2; ++kh) {
            bf16x8 bh = *(const bf16x8*)&woh[(jt * 16 + m) * WOS + kh * 32 + quad * 8];
            bf16x8 bl = *(const bf16x8*)&wol[(jt * 16 + m) * WOS + kh * 32 + quad * 8];
            acc[jt] = MFMA_BF16(ah[kh], bh, acc[jt], 0, 0, 0);
            acc[jt] = MFMA_BF16(al[kh], bh, acc[jt], 0, 0, 0);
            acc[jt] = MFMA_BF16(ah[kh], bl, acc[jt], 0, 0, 0);
        }
    }

    #pragma unroll
    for (int jt = 0; jt < 4; ++jt) {
        const float b = sb[jt * 16 + m];
        #pragma unroll
        for (int r = 0; r < 4; ++r)
            out[(p0 + r0 + quad * 4 + r) * 64 + jt * 16 + m] = acc[jt][r] + b;
    }
}

// ---------------------------------------------------------------------------
extern "C" void kernel_launch(void* const* d_in, const int* in_sizes, int n_in,
                              void* d_out, int out_size, void* d_ws, size_t ws_size,
                              hipStream_t stream)
{
    (void)in_sizes; (void)n_in; (void)out_size; (void)ws_size;
    const float* values = (const float*)d_in[0];
    const float* keys   = (const float*)d_in[1];
    const float* query  = (const float*)d_in[2];
    const float* Wv     = (const float*)d_in[3];
    const float* Wk     = (const float*)d_in[4];
    const float* Wq     = (const float*)d_in[5];
    const float* Wo     = (const float*)d_in[6];
    const float* bo     = (const float*)d_in[7];

    const size_t TOT = (size_t)144 * N_NODES * 16;   // 2,359,296 bf16 per plane
    unsigned short* ws16 = (unsigned short*)d_ws;
    unsigned short* qhi  = ws16;
    unsigned short* qlo  = ws16 + 1*TOT;
    unsigned short* khi  = ws16 + 2*TOT;
    unsigned short* klo  = ws16 + 3*TOT;
    unsigned short* vthi = ws16 + 4*TOT;
    unsigned short* vtlo = ws16 + 5*TOT;
    unsigned short* obh  = ws16 + 6*TOT;
    unsigned short* obl  = ws16 + 7*TOT;             // total ws = 8*TOT*2B = 37.75 MB

    proj5_kernel<<<dim3(288, 3), 128, 0, stream>>>(values, keys, query, Wv, Wk, Wq,
                                                   qhi, qlo, khi, klo, vthi, vtlo);
    attn_mfma4_kernel<<<dim3(16 * 144), 128, 0, stream>>>(qhi, qlo, khi, klo, vthi, vtlo,
                                                          obh, obl);
    outproj_mfma_kernel<<<dim3(576), 256, 0, stream>>>(obh, obl, Wo, bo, (float*)d_out);
}